// Round 7
// baseline (238.712 us; speedup 1.0000x reference)
//
#include <hip/hip_runtime.h>
#include <hip/hip_bf16.h>

#define DEVI static __device__ __forceinline__

typedef __attribute__((ext_vector_type(4))) float f32x4;
typedef __attribute__((ext_vector_type(8))) short bf16x8;
typedef __attribute__((ext_vector_type(4))) short s16x4;

constexpr int TB  = 2;      // batch
constexpr int TS  = 2048;   // seq len
constexpr int TD  = 1024;   // model dim
constexpr int TH  = 16;     // heads
constexpr int TDH = 64;     // head dim
constexpr int TC  = 64;     // window size
constexpr int TFF = 4096;   // ffn dim
constexpr int TM  = TB * TS;  // 4096 rows

DEVI float bf2f(short s) {
  return __builtin_bit_cast(float, (unsigned)((unsigned short)s) << 16);
}
DEVI short f2bf(float f) {
  return __builtin_bit_cast(short, __float2bfloat16(f));
}

// async global->LDS, 16B per lane, dest = wave-uniform base + lane*16
#define GLD16(gp, lp)                                              \
  __builtin_amdgcn_global_load_lds(                                \
      (const __attribute__((address_space(1))) void*)(gp),         \
      (__attribute__((address_space(3))) void*)(lp), 16, 0, 0)

// counted vmcnt wait (N = max loads allowed outstanding), compiler-fenced
#define WAITVM(N) asm volatile("s_waitcnt vmcnt(" #N ")" ::: "memory")

// ---------------- all weight transposes in ONE dispatch -------------------
__global__ __launch_bounds__(256) void k_trans_all(
    const float* __restrict__ Wq, const float* __restrict__ Wk,
    const float* __restrict__ Wv, const float* __restrict__ Wo,
    const float* __restrict__ W1, const float* __restrict__ W2,
    __hip_bfloat16* __restrict__ WqkvT, __hip_bfloat16* __restrict__ WoT,
    __hip_bfloat16* __restrict__ W1T, __hip_bfloat16* __restrict__ W2T) {
  __shared__ float tile[32][33];
  int bid = blockIdx.x;
  const float* src; __hip_bfloat16* dst;
  int K, N, n0, k0;
  if (bid < 4096) {                      // Wq,Wk,Wv,Wo : 1024x1024 each
    int m = bid >> 10, t = bid & 1023;
    src = (m == 0) ? Wq : (m == 1) ? Wk : (m == 2) ? Wv : Wo;
    dst = (m == 3) ? WoT : WqkvT + (size_t)m * TD * TD;
    K = TD; N = TD; n0 = (t & 31) * 32; k0 = (t >> 5) * 32;
  } else if (bid < 8192) {               // W1 : 1024x4096
    int t = bid - 4096;
    src = W1; dst = W1T; K = TD; N = TFF;
    n0 = (t & 127) * 32; k0 = (t >> 7) * 32;
  } else {                               // W2 : 4096x1024
    int t = bid - 8192;
    src = W2; dst = W2T; K = TFF; N = TD;
    n0 = (t & 31) * 32; k0 = (t >> 5) * 32;
  }
  int tx = threadIdx.x & 31, ty = threadIdx.x >> 5;  // 32 x 8
  for (int i = 0; i < 32; i += 8)
    tile[ty + i][tx] = src[(size_t)(k0 + ty + i) * N + n0 + tx];
  __syncthreads();
  for (int i = 0; i < 32; i += 8)
    dst[(size_t)(n0 + ty + i) * K + k0 + tx] = __float2bfloat16(tile[tx][ty + i]);
}

// ---------------- h = x + pos[t % C] (bf16 only) --------------------------
__global__ __launch_bounds__(256) void k_addpos(
    const float* __restrict__ x, const float* __restrict__ pos,
    __hip_bfloat16* __restrict__ hb, int total4) {
  int i = blockIdx.x * 256 + threadIdx.x;
  if (i >= total4) return;
  int e = i * 4;
  int d = e & (TD - 1);
  int t = (e / TD) & (TS - 1);
  f32x4 xv = *(const f32x4*)(x + e);
  f32x4 pv = *(const f32x4*)(pos + (size_t)(t & (TC - 1)) * TD + d);
  s16x4 hb4;
  for (int j = 0; j < 4; j++) hb4[j] = f2bf(xv[j] + pv[j]);
  *(s16x4*)((short*)hb + e) = hb4;
}

// ---------------- bf16 MFMA GEMM: 1 barrier/tile + register ping-pong -----
// C = A(MxK) * BT(NxK)^T.  BM=256, BK=32, 512 thr = 8 waves.
// BN=256: waves 2m x 4n (wave-C 128x64, MT=8 A-frags).
// BN=128: waves 4m x 2n (wave-C  64x64, MT=4 A-frags).
// Ring-4 LDS tile buffers; iter t:
//   WAITVM(LPT)  [own tile-(t+1) loads landed; t+2 stays in flight]
//   s_barrier    [=> ALL waves' t+1 landed; all reads of buf[(t-1)&3] done:
//                 they were lgkm-waited before MFMA(t-1), which precedes
//                 each wave's arrival here]
//   stage(t+3) -> buf[(t+3)&3] (== (t-1)&3, free per above)
//   ds_read B(t+1) -> bnxt     (consumed NEXT iter => full-iter latency cover)
//   { ds_read A(t) 4-frag batch ; 16 MFMA w/ bcur } x (MT/4)   [same interval]
//   bcur = bnxt
// Loads never drained in steady state (T4); setprio (T5) around MFMA.
// Swizzle: LDS slot s of row r holds k-octet s^((r>>1)&3) (0-conflict, r4-r6).
// EPI: 0 = store bf16, 1 = bias+relu bf16, 2 = f32 split-K partial.
template <int BN, int EPI>
__global__ __launch_bounds__(512, 2) void k_gemm9(
    const __hip_bfloat16* __restrict__ A, const __hip_bfloat16* __restrict__ BT,
    void* __restrict__ Cout, const float* __restrict__ bias,
    int M, int N, int K, int lda, int ldb) {
  constexpr int BM = 256, BK = 32;
  constexpr int MT  = (BN == 256) ? 8 : 4;    // A-frags per wave per tile
  constexpr int WMR = (BN == 256) ? 128 : 64; // wave m-rows
  __shared__ __align__(16) short As[4][BM * BK];  // 4 x 16 KB
  __shared__ __align__(16) short Bs[4][BN * BK];  // 4 x (16 | 8) KB
  int tid = threadIdx.x, lane = tid & 63, wave = tid >> 6;
  int wm = (BN == 256) ? (wave >> 2) : (wave >> 1);
  int wn = (BN == 256) ? (wave & 3) : (wave & 1);
  int fr = lane & 15, fg = lane >> 4;
  int m0 = blockIdx.x * BM, n0 = blockIdx.y * BN;
  size_t koff = (size_t)blockIdx.z * K;
  const short* Ab = (const short*)A + koff;
  const short* Bb = (const short*)BT + koff;

  // per-thread staging source pointers (row r, pre-swizzled k-octet)
  int r0 = tid >> 2, s0 = (tid & 3) ^ ((r0 >> 1) & 3);
  int r1 = 128 + r0, s1 = (tid & 3) ^ ((r1 >> 1) & 3);
  const short* pA0 = Ab + (size_t)(m0 + r0) * lda + s0 * 8;
  const short* pA1 = Ab + (size_t)(m0 + r1) * lda + s1 * 8;
  const short* pB0 = Bb + (size_t)(n0 + r0) * ldb + s0 * 8;
  const short* pB1 = (BN == 256) ? Bb + (size_t)(n0 + r1) * ldb + s1 * 8 : pB0;
  int dst0 = (wave * 64) * 16;
  int dst1 = (512 + wave * 64) * 16;

  auto stage = [&](int d, int T) {
    GLD16(pA0 + T * BK, (char*)&As[d][0] + dst0);
    GLD16(pA1 + T * BK, (char*)&As[d][0] + dst1);
    GLD16(pB0 + T * BK, (char*)&Bs[d][0] + dst0);
    if constexpr (BN == 256) GLD16(pB1 + T * BK, (char*)&Bs[d][0] + dst1);
  };
  auto readB = [&](int d, bf16x8* b) {
#pragma unroll
    for (int n = 0; n < 4; n++) {
      int row = wn * 64 + n * 16 + fr;
      b[n] = *(const bf16x8*)((const char*)&Bs[d][0] + row * 64 +
                              ((fg ^ ((row >> 1) & 3)) << 4));
    }
  };

  f32x4 acc[MT][4];
#pragma unroll
  for (int m = 0; m < MT; m++)
#pragma unroll
    for (int n = 0; n < 4; n++) acc[m][n] = f32x4{0.f, 0.f, 0.f, 0.f};

  const int nt = K / BK;  // >= 16 for all shapes used
  stage(0, 0);
  stage(1, 1);
  if (BN == 256) { WAITVM(4); } else { WAITVM(3); }  // tile 0 landed
  __builtin_amdgcn_s_barrier();
  asm volatile("" ::: "memory");
  stage(2, 2);

  bf16x8 bcur[4], bnxt[4];
  readB(0, bcur);

  for (int t = 0; t < nt; t++) {
    const char* Al = (const char*)&As[t & 3][0];
    if (t + 1 < nt) {
      if (t + 2 < nt) {
        if (BN == 256) { WAITVM(4); } else { WAITVM(3); }  // t+1 landed
      } else {
        WAITVM(0);
      }
      __builtin_amdgcn_s_barrier();
      asm volatile("" ::: "memory");
      if (t + 3 < nt) stage((t + 3) & 3, t + 3);
      readB((t + 1) & 3, bnxt);
    }
#pragma unroll
    for (int h = 0; h < MT / 4; h++) {
      bf16x8 af[4];
#pragma unroll
      for (int mt = 0; mt < 4; mt++) {
        int row = wm * WMR + h * 64 + mt * 16 + fr;
        af[mt] = *(const bf16x8*)(Al + row * 64 + ((fg ^ ((row >> 1) & 3)) << 4));
      }
      __builtin_amdgcn_s_setprio(1);
#pragma unroll
      for (int mt = 0; mt < 4; mt++)
#pragma unroll
        for (int n = 0; n < 4; n++)
          acc[h * 4 + mt][n] = __builtin_amdgcn_mfma_f32_16x16x32_bf16(
              af[mt], bcur[n], acc[h * 4 + mt][n], 0, 0, 0);
      __builtin_amdgcn_s_setprio(0);
    }
    if (t + 1 < nt) {
#pragma unroll
      for (int n = 0; n < 4; n++) bcur[n] = bnxt[n];
    }
  }

  float* Cf = (float*)Cout + (size_t)blockIdx.z * M * N;
#pragma unroll
  for (int mt = 0; mt < MT; mt++)
#pragma unroll
    for (int n = 0; n < 4; n++) {
      int col = n0 + wn * 64 + n * 16 + fr;
      float bv = (EPI == 1) ? bias[col] : 0.f;
#pragma unroll
      for (int j = 0; j < 4; j++) {
        int row = m0 + wm * WMR + (mt >> 2) * 64 + (mt & 3) * 16 + fg * 4 + j;
        float v = acc[mt][n][j];
        if (EPI == 1) { v += bv; v = fmaxf(v, 0.f); }
        if (EPI == 2)
          Cf[(size_t)row * N + col] = v;
        else
          ((__hip_bfloat16*)Cout)[(size_t)row * N + col] = __float2bfloat16(v);
      }
    }
}

// ---------------- V transpose: qkv v-slice -> vT[bh][64 d][2048 t] --------
__global__ __launch_bounds__(256) void k_vtrans(
    const __hip_bfloat16* __restrict__ qkv, __hip_bfloat16* __restrict__ vT) {
  __shared__ short tile[64][68];  // [t][d], pad->136B row stride
  int bh = blockIdx.x;            // b*16+h
  int tb = blockIdx.y;            // 64-row t block
  int b = bh >> 4, h = bh & 15;
  int tid = threadIdx.x;
#pragma unroll
  for (int i = 0; i < 2; i++) {
    int c = i * 256 + tid;        // 512 chunks of 8 elems
    int trow = c >> 3, seg = c & 7;
    bf16x8 v = *(const bf16x8*)((const short*)qkv +
        (size_t)(b * TS + tb * 64 + trow) * 3072 + 2048 + h * TDH + seg * 8);
    s16x4 lo = {v[0], v[1], v[2], v[3]}, hi = {v[4], v[5], v[6], v[7]};
    *(s16x4*)&tile[trow][seg * 8] = lo;
    *(s16x4*)&tile[trow][seg * 8 + 4] = hi;
  }
  __syncthreads();
#pragma unroll
  for (int i2 = 0; i2 < 2; i2++) {
    int c = i2 * 256 + tid;
    int d = c >> 3, ts = c & 7;   // output row d, t-chunk ts
    bf16x8 o;
#pragma unroll
    for (int j = 0; j < 8; j++) o[j] = tile[ts * 8 + j][d];
    *(bf16x8*)((short*)vT + (size_t)bh * TDH * TS + (size_t)d * TS +
               tb * 64 + ts * 8) = o;
  }
}

// ---------------- sliding-window attention (MFMA) --------------------------
__global__ __launch_bounds__(256) void k_attn(
    const __hip_bfloat16* __restrict__ qkv, const __hip_bfloat16* __restrict__ vT,
    const float* __restrict__ rpe, __hip_bfloat16* __restrict__ out) {
  __shared__ __align__(16) short K_lds[128 * 64];    // [jj][64k], swz
  __shared__ __align__(16) short VT_lds[64 * 128];   // [d][128jj], swz
  __shared__ __align__(16) short P_lds[4][16 * 136]; // per-wave [q][jj], pad
  __shared__ float rpe_lds[TC];
  int tid = threadIdx.x, lane = tid & 63, wave = tid >> 6;
  int fr = lane & 15, g = lane >> 4;
  int blk = blockIdx.x;           // (b*16+h)*32 + qt
  int qt = blk & 31, bh = blk >> 5;
  int h = bh & 15, b = bh >> 4;
  int t0 = qt * 64;
  const short* qg = (const short*)qkv;

  if (tid < TC) rpe_lds[tid] = rpe[h * TC + tid];

#pragma unroll
  for (int i = 0; i < 4; i++) {
    int cb = i * 256 + wave * 64;
    int c = cb + lane;
    int row = c >> 3, slot = c & 7;
    int seg = slot ^ (row & 7);
    int kr = t0 - 64 + row; if (kr < 0) kr = 0;
    GLD16(qg + ((size_t)(b * TS + kr) * 3072 + 1024 + h * TDH + seg * 8),
          (char*)K_lds + cb * 16);
  }
  const short* vg = (const short*)vT + (size_t)bh * TDH * TS;
#pragma unroll
  for (int i = 0; i < 4; i++) {
    int cb = i * 256 + wave * 64;
    int c = cb + lane;
    int row = c >> 4, slot = c & 15;
    int seg = slot ^ (row & 15);
    int tc = t0 - 64 + seg * 8; if (tc < 0) tc = 0;
    GLD16(vg + (size_t)row * TS + tc, (char*)VT_lds + cb * 16);
  }

  int qrow = t0 + wave * 16 + fr;
  const short* qptr = qg + ((size_t)(b * TS + qrow) * 3072 + h * TDH + g * 8);
  bf16x8 qf0 = *(const bf16x8*)qptr;
  bf16x8 qf1 = *(const bf16x8*)(qptr + 32);

  __syncthreads();  // drains GLD16 (vmcnt) + barrier

  f32x4 S[8] = {};
#pragma unroll
  for (int kk = 0; kk < 2; kk++) {
    bf16x8 a = kk ? qf1 : qf0;
#pragma unroll
    for (int nt = 0; nt < 8; nt++) {
      int row = nt * 16 + fr;
      int slot = (kk * 4 + g) ^ (row & 7);
      bf16x8 bfrag = *(const bf16x8*)((const char*)K_lds + row * 128 + slot * 16);
      S[nt] = __builtin_amdgcn_mfma_f32_16x16x32_bf16(a, bfrag, S[nt], 0, 0, 0);
    }
  }

  int wq = wave * 16;
#pragma unroll
  for (int r = 0; r < 4; r++) {
    int ql = g * 4 + r;
    float sc[8];
    float m = -3.4028235e38f;
#pragma unroll
    for (int nt = 0; nt < 8; nt++) {
      int jj = nt * 16 + fr;
      int d = wq + ql + 64 - jj;
      bool valid = (d >= 0) && (d < TC) && (t0 - 64 + jj >= 0);
      float v = valid ? (S[nt][r] * 0.125f + rpe_lds[d & (TC - 1)])
                      : -3.4028235e38f;
      sc[nt] = v;
      m = fmaxf(m, v);
    }
#pragma unroll
    for (int o = 1; o < 16; o <<= 1) m = fmaxf(m, __shfl_xor(m, o));
    float p[8], sum = 0.f;
#pragma unroll
    for (int nt = 0; nt < 8; nt++) { p[nt] = __expf(sc[nt] - m); sum += p[nt]; }
#pragma unroll
    for (int o = 1; o < 16; o <<= 1) sum += __shfl_xor(sum, o);
    float rs = 1.0f / sum;
#pragma unroll
    for (int nt = 0; nt < 8; nt++)
      P_lds[wave][ql * 136 + nt * 16 + fr] = f2bf(p[nt] * rs);
  }

  f32x4 O[4] = {};
#pragma unroll
  for (int kk = 0; kk < 4; kk++) {
    bf16x8 pa = *(const bf16x8*)((const char*)&P_lds[wave][0] +
                                 fr * 272 + kk * 64 + g * 16);
#pragma unroll
    for (int dt = 0; dt < 4; dt++) {
      int row = dt * 16 + fr;
      int slot = (kk * 4 + g) ^ (row & 15);
      bf16x8 vb = *(const bf16x8*)((const char*)VT_lds + row * 256 + slot * 16);
      O[dt] = __builtin_amdgcn_mfma_f32_16x16x32_bf16(pa, vb, O[dt], 0, 0, 0);
    }
  }

  size_t ob = ((size_t)(b * TS + t0 + wq + g * 4)) * TD + h * TDH;
#pragma unroll
  for (int dt = 0; dt < 4; dt++)
#pragma unroll
    for (int r = 0; r < 4; r++)
      ((short*)out)[ob + (size_t)r * TD + dt * 16 + fr] = f2bf(O[dt][r]);
}

// ---------------- LayerNorm (two-pass, fused residual + split-K sum) ------
DEVI float block_sum(float v, float* red) {
  for (int o = 32; o; o >>= 1) v += __shfl_xor(v, o);
  int wave = threadIdx.x >> 6;
  if ((threadIdx.x & 63) == 0) red[wave] = v;
  __syncthreads();
  float r = red[0] + red[1] + red[2] + red[3];
  __syncthreads();
  return r;
}

__global__ __launch_bounds__(256) void k_ln1(
    const float* __restrict__ x, const float* __restrict__ pos,
    const float* __restrict__ P0, const float* __restrict__ P1,
    const float* __restrict__ scale, const float* __restrict__ offset,
    float* __restrict__ outf, __hip_bfloat16* __restrict__ outb) {
  __shared__ float red[4];
  int row = blockIdx.x, tid = threadIdx.x;
  int t = row & (TS - 1), pr = t & (TC - 1);
  size_t base = (size_t)row * TD + tid * 4;
  f32x4 xv = *(const f32x4*)(x + base);
  f32x4 pv = *(const f32x4*)(pos + (size_t)pr * TD + tid * 4);
  f32x4 a0 = *(const f32x4*)(P0 + base);
  f32x4 a1 = *(const f32x4*)(P1 + base);
  xv = xv + pv + a0 + a1;
  float s = xv[0] + xv[1] + xv[2] + xv[3];
  s = block_sum(s, red);
  float mu = s * (1.f / TD);
  float s2 = 0.f;
  for (int j = 0; j < 4; j++) { float dlt = xv[j] - mu; s2 += dlt * dlt; }
  s2 = block_sum(s2, red);
  float rs = rsqrtf(s2 * (1.f / TD) + 1e-5f);
  f32x4 sc = *(const f32x4*)(scale + tid * 4);
  f32x4 of = *(const f32x4*)(offset + tid * 4);
  f32x4 y;
  for (int j = 0; j < 4; j++) y[j] = (xv[j] - mu) * rs * sc[j] + of[j];
  *(f32x4*)(outf + base) = y;
  s16x4 pb;
  for (int j = 0; j < 4; j++) pb[j] = f2bf(y[j]);
  *(s16x4*)((short*)outb + base) = pb;
}

__global__ __launch_bounds__(256) void k_ln2(
    const float* __restrict__ P0, const float* __restrict__ P1,
    const float* __restrict__ R, const float* __restrict__ bias,
    const float* __restrict__ scale, const float* __restrict__ offset,
    float* __restrict__ outf) {
  __shared__ float red[4];
  int row = blockIdx.x, tid = threadIdx.x;
  size_t base = (size_t)row * TD + tid * 4;
  f32x4 a0 = *(const f32x4*)(P0 + base);
  f32x4 a1 = *(const f32x4*)(P1 + base);
  f32x4 rv = *(const f32x4*)(R + base);
  f32x4 bi = *(const f32x4*)(bias + tid * 4);
  f32x4 xv = a0 + a1 + rv + bi;
  float s = xv[0] + xv[1] + xv[2] + xv[3];
  s = block_sum(s, red);
  float mu = s * (1.f / TD);
  float s2 = 0.f;
  for (int j = 0; j < 4; j++) { float dlt = xv[j] - mu; s2 += dlt * dlt; }
  s2 = block_sum(s2, red);
  float rs = rsqrtf(s2 * (1.f / TD) + 1e-5f);
  f32x4 sc = *(const f32x4*)(scale + tid * 4);
  f32x4 of = *(const f32x4*)(offset + tid * 4);
  f32x4 y;
  for (int j = 0; j < 4; j++) y[j] = (xv[j] - mu) * rs * sc[j] + of[j];
  *(f32x4*)(outf + base) = y;
}

// --------------------------------------------------------------------------
extern "C" void kernel_launch(void* const* d_in, const int* in_sizes, int n_in,
                              void* d_out, int out_size, void* d_ws, size_t ws_size,
                              hipStream_t stream) {
  const float* x    = (const float*)d_in[0];
  const float* pos  = (const float*)d_in[2];
  const float* rpe  = (const float*)d_in[3];
  const float* Wq   = (const float*)d_in[4];
  const float* Wk   = (const float*)d_in[5];
  const float* Wv   = (const float*)d_in[6];
  const float* Wo   = (const float*)d_in[7];
  const float* ln1s = (const float*)d_in[8];
  const float* ln1o = (const float*)d_in[9];
  const float* W1   = (const float*)d_in[10];
  const float* b1   = (const float*)d_in[11];
  const float* W2   = (const float*)d_in[12];
  const float* b2   = (const float*)d_in[13];
  const float* ln2s = (const float*)d_in[14];
  const float* ln2o = (const float*)d_in[15];

  char* ws = (char*)d_ws;
  const size_t MB = 1ull << 20;
  __hip_bfloat16* WqkvT = (__hip_bfloat16*)(ws + 0 * MB);   // 6 MB
  __hip_bfloat16* WoT   = (__hip_bfloat16*)(ws + 6 * MB);   // 2 MB
  __hip_bfloat16* W1T   = (__hip_bfloat16*)(ws + 8 * MB);   // 8 MB
  __hip_bfloat16* W2T   = (__hip_bfloat16*)(ws + 16 * MB);  // 8 MB
  __hip_bfloat16* hB    = (__hip_bfloat16*)(ws + 24 * MB);  // 8 MB (dead after QKV)
  __hip_bfloat16* qkv   = (__hip_bfloat16*)(ws + 32 * MB);  // 24 MB (dead after attn)
  __hip_bfloat16* aoB   = (__hip_bfloat16*)(ws + 56 * MB);  // 8 MB (dead after Wo)
  float*          oF2   = (float*)(ws + 64 * MB);           // 32 MB (dead after ln1)
  float*          atF   = (float*)(ws + 96 * MB);           // 16 MB
  __hip_bfloat16* atB   = (__hip_bfloat16*)(ws + 24 * MB);  // 8 MB (aliases hB)
  __hip_bfloat16* ff1   = (__hip_bfloat16*)(ws + 32 * MB);  // 32 MB (aliases qkv+aoB)
  float*          ff2   = (float*)(ws + 64 * MB);           // 32 MB (aliases oF2)
  __hip_bfloat16* vTb   = (__hip_bfloat16*)(ws + 112 * MB); // 8 MB (dead after attn)
  // high-water: 120 MB

  dim3 blk(256), blk5(512);

  k_trans_all<<<12288, blk, 0, stream>>>(Wq, Wk, Wv, Wo, W1, W2,
                                         WqkvT, WoT, W1T, W2T);

  k_addpos<<<(TM * TD / 4 + 255) / 256, blk, 0, stream>>>(x, pos, hB, TM * TD / 4);

  // QKV fused: (4096 x 1024) * (3072 x 1024)^T -> bf16 qkv
  k_gemm9<256, 0><<<dim3(TM / 256, 3072 / 256, 1), blk5, 0, stream>>>(
      hB, WqkvT, qkv, nullptr, TM, 3072, TD, TD, TD);

  k_vtrans<<<dim3(TB * TH, TS / 64), blk, 0, stream>>>(qkv, vTb);
  k_attn<<<TB * TH * (TS / 64), blk, 0, stream>>>(qkv, vTb, rpe, aoB);

  // Wo: BN=128, split-K=2 -> two f32 partials (grid 16x8x2 = 256 blocks)
  k_gemm9<128, 2><<<dim3(TM / 256, TD / 128, 2), blk5, 0, stream>>>(
      aoB, WoT, oF2, nullptr, TM, TD, TD / 2, TD, TD);

  k_ln1<<<TM, blk, 0, stream>>>(x, pos, oF2, oF2 + (size_t)TM * TD, ln1s, ln1o, atF, atB);

  // FFN1: bias+relu -> bf16 (grid 16x16 = 256 blocks)
  k_gemm9<256, 1><<<dim3(TM / 256, TFF / 256, 1), blk5, 0, stream>>>(
      atB, W1T, ff1, b1, TM, TFF, TD, TD, TD);

  // FFN2: BN=128, split-K=2 -> two f32 partials (grid 16x8x2 = 256 blocks)
  k_gemm9<128, 2><<<dim3(TM / 256, TD / 128, 2), blk5, 0, stream>>>(
      ff1, W2T, ff2, nullptr, TM, TD, TFF / 2, TFF, TFF);

  k_ln2<<<TM, blk, 0, stream>>>(ff2, ff2 + (size_t)TM * TD, atF, b2, ln2s, ln2o,
                                (float*)d_out);
}

// Round 8
// 205.551 us; speedup vs baseline: 1.1613x; 1.1613x over previous
//
#include <hip/hip_runtime.h>
#include <hip/hip_bf16.h>

#define DEVI static __device__ __forceinline__

typedef __attribute__((ext_vector_type(4))) float f32x4;
typedef __attribute__((ext_vector_type(8))) short bf16x8;
typedef __attribute__((ext_vector_type(4))) short s16x4;

constexpr int TB  = 2;      // batch
constexpr int TS  = 2048;   // seq len
constexpr int TD  = 1024;   // model dim
constexpr int TH  = 16;     // heads
constexpr int TDH = 64;     // head dim
constexpr int TC  = 64;     // window size
constexpr int TFF = 4096;   // ffn dim
constexpr int TM  = TB * TS;  // 4096 rows

DEVI float bf2f(short s) {
  return __builtin_bit_cast(float, (unsigned)((unsigned short)s) << 16);
}
DEVI short f2bf(float f) {
  return __builtin_bit_cast(short, __float2bfloat16(f));
}

// async global->LDS, 16B per lane, dest = wave-uniform base + lane*16
#define GLD16(gp, lp)                                              \
  __builtin_amdgcn_global_load_lds(                                \
      (const __attribute__((address_space(1))) void*)(gp),         \
      (__attribute__((address_space(3))) void*)(lp), 16, 0, 0)

// counted vmcnt wait (N = max loads allowed outstanding), compiler-fenced
#define WAITVM(N) asm volatile("s_waitcnt vmcnt(" #N ")" ::: "memory")

// ---------------- weight transposes + addpos in ONE dispatch --------------
__global__ __launch_bounds__(256) void k_trans_all(
    const float* __restrict__ Wq, const float* __restrict__ Wk,
    const float* __restrict__ Wv, const float* __restrict__ Wo,
    const float* __restrict__ W1, const float* __restrict__ W2,
    __hip_bfloat16* __restrict__ WqkvT, __hip_bfloat16* __restrict__ WoT,
    __hip_bfloat16* __restrict__ W1T, __hip_bfloat16* __restrict__ W2T,
    const float* __restrict__ x, const float* __restrict__ pos,
    __hip_bfloat16* __restrict__ hb) {
  int bid = blockIdx.x;
  if (bid >= 12288) {                    // addpos: h = x + pos[t % C]
    int i = (bid - 12288) * 256 + threadIdx.x;
    int e = i * 4;
    int d = e & (TD - 1);
    int t = (e / TD) & (TS - 1);
    f32x4 xv = *(const f32x4*)(x + e);
    f32x4 pv = *(const f32x4*)(pos + (size_t)(t & (TC - 1)) * TD + d);
    s16x4 hb4;
    for (int j = 0; j < 4; j++) hb4[j] = f2bf(xv[j] + pv[j]);
    *(s16x4*)((short*)hb + e) = hb4;
    return;
  }
  __shared__ float tile[32][33];
  const float* src; __hip_bfloat16* dst;
  int K, N, n0, k0;
  if (bid < 4096) {                      // Wq,Wk,Wv,Wo : 1024x1024 each
    int m = bid >> 10, t = bid & 1023;
    src = (m == 0) ? Wq : (m == 1) ? Wk : (m == 2) ? Wv : Wo;
    dst = (m == 3) ? WoT : WqkvT + (size_t)m * TD * TD;
    K = TD; N = TD; n0 = (t & 31) * 32; k0 = (t >> 5) * 32;
  } else if (bid < 8192) {               // W1 : 1024x4096
    int t = bid - 4096;
    src = W1; dst = W1T; K = TD; N = TFF;
    n0 = (t & 127) * 32; k0 = (t >> 7) * 32;
  } else {                               // W2 : 4096x1024
    int t = bid - 8192;
    src = W2; dst = W2T; K = TFF; N = TD;
    n0 = (t & 31) * 32; k0 = (t >> 5) * 32;
  }
  int tx = threadIdx.x & 31, ty = threadIdx.x >> 5;  // 32 x 8
  for (int i = 0; i < 32; i += 8)
    tile[ty + i][tx] = src[(size_t)(k0 + ty + i) * N + n0 + tx];
  __syncthreads();
  for (int i = 0; i < 32; i += 8)
    dst[(size_t)(n0 + ty + i) * K + k0 + tx] = __float2bfloat16(tile[tx][ty + i]);
}

// ---------------- bf16 MFMA GEMM: 8-phase-style, ring-4, counted vmcnt ----
// r6-proven structure, unchanged schedule.  NEW: T1 XCD-aware bijective
// block remap (grid sizes are multiples of 8; gx==16 divisible by 8):
// phys -> logical = (phys%8)*chunk + phys/8, so each XCD owns a contiguous
// logical range; logical decomposed m-supertile-of-8 first so each XCD's
// blocks form a compact 8m x (2-4)n rectangle sharing A/B panels in its L2.
// EPI: 0 = store bf16, 1 = bias+relu bf16, 2 = f32 split-K partial.
template <int BN, int EPI>
__global__ __launch_bounds__(512, 2) void k_gemm8(
    const __hip_bfloat16* __restrict__ A, const __hip_bfloat16* __restrict__ BT,
    void* __restrict__ Cout, const float* __restrict__ bias,
    int M, int N, int K, int lda, int ldb) {
  constexpr int BM = 256, BK = 32;
  constexpr int FN = BN / 64;                  // n-frags per wave: 4 or 2
  __shared__ __align__(16) short As[4][BM * BK];  // 4 x 16 KB
  __shared__ __align__(16) short Bs[4][BN * BK];  // 4 x (16 | 8) KB
  int tid = threadIdx.x, lane = tid & 63, wave = tid >> 6;
  int wm = wave >> 2, wn = wave & 3;           // 2 x 4 wave grid
  int fr = lane & 15, fg = lane >> 4;

  // ---- T1: XCD-aware bijective remap ----
  int bx, by, bz;
  {
    int gx = gridDim.x, gy = gridDim.y;
    int nb = gx * gy * gridDim.z;
    int phys = blockIdx.x + gx * (blockIdx.y + gy * blockIdx.z);
    int chunk = nb >> 3;
    int logical = (phys & 7) * chunk + (phys >> 3);
    int perz = gx * gy;
    bz = logical / perz;
    int l2 = logical - bz * perz;
    int g = l2 / (8 * gy);
    int r = l2 - g * 8 * gy;
    by = r >> 3;
    bx = g * 8 + (r & 7);
  }
  int m0 = bx * BM, n0 = by * BN;
  size_t koff = (size_t)bz * K;
  const short* Ab = (const short*)A + koff;
  const short* Bb = (const short*)BT + koff;

  // per-thread staging source pointers; tile T advances by T*BK shorts
  int r0 = tid >> 2, s0 = (tid & 3) ^ ((r0 >> 1) & 3);
  int r1 = 128 + r0, s1 = (tid & 3) ^ ((r1 >> 1) & 3);
  const short* pA0 = Ab + (size_t)(m0 + r0) * lda + s0 * 8;
  const short* pA1 = Ab + (size_t)(m0 + r1) * lda + s1 * 8;
  const short* pB0 = Bb + (size_t)(n0 + r0) * ldb + s0 * 8;
  const short* pB1 = (BN == 256) ? Bb + (size_t)(n0 + r1) * ldb + s1 * 8 : pB0;
  int dst0 = (wave * 64) * 16;                 // LDS byte offsets
  int dst1 = (512 + wave * 64) * 16;

  auto stageA = [&](int d, int T) {
    GLD16(pA0 + T * BK, (char*)&As[d][0] + dst0);
    GLD16(pA1 + T * BK, (char*)&As[d][0] + dst1);
  };
  auto stageB = [&](int d, int T) {
    GLD16(pB0 + T * BK, (char*)&Bs[d][0] + dst0);
    if constexpr (BN == 256) GLD16(pB1 + T * BK, (char*)&Bs[d][0] + dst1);
  };

  f32x4 acc[8][FN];
#pragma unroll
  for (int m = 0; m < 8; m++)
#pragma unroll
    for (int n = 0; n < FN; n++) acc[m][n] = f32x4{0.f, 0.f, 0.f, 0.f};

  const int nt = K / BK;  // >= 16 for all shapes used
  stageA(0, 0); stageB(0, 0);
  stageA(1, 1); stageB(1, 1);
  stageA(2, 2); stageB(2, 2);
  if (BN == 256) { WAITVM(8); } else { WAITVM(6); }  // tile 0 landed; 1,2 in flight
  __builtin_amdgcn_s_barrier();

  for (int t = 0; t < nt; t++) {
    int d = t & 3, pf = (t + 3) & 3;
    bool dopf = (t + 3) < nt;
    const char* Al = (const char*)&As[d][0];
    const char* Bl = (const char*)&Bs[d][0];
    if constexpr (BN == 256) {
      bf16x8 a[4], b[4];
      // ---- phase 0: m-half 0, load B frags (reused in phase 1) ----
#pragma unroll
      for (int mt = 0; mt < 4; mt++) {
        int row = wm * 128 + mt * 16 + fr;
        a[mt] = *(const bf16x8*)(Al + row * 64 + ((fg ^ ((row >> 1) & 3)) << 4));
      }
#pragma unroll
      for (int n = 0; n < 4; n++) {
        int row = wn * 64 + n * 16 + fr;
        b[n] = *(const bf16x8*)(Bl + row * 64 + ((fg ^ ((row >> 1) & 3)) << 4));
      }
      if (dopf) stageA(pf, t + 3);
      __builtin_amdgcn_s_barrier();
      __builtin_amdgcn_s_setprio(1);
#pragma unroll
      for (int mt = 0; mt < 4; mt++)
#pragma unroll
        for (int n = 0; n < 4; n++)
          acc[mt][n] = __builtin_amdgcn_mfma_f32_16x16x32_bf16(a[mt], b[n],
                                                               acc[mt][n], 0, 0, 0);
      __builtin_amdgcn_s_setprio(0);
      __builtin_amdgcn_s_barrier();
      // ---- phase 1: m-half 1 ----
#pragma unroll
      for (int mt = 0; mt < 4; mt++) {
        int row = wm * 128 + 64 + mt * 16 + fr;
        a[mt] = *(const bf16x8*)(Al + row * 64 + ((fg ^ ((row >> 1) & 3)) << 4));
      }
      if (dopf) stageB(pf, t + 3);
      if (t < nt - 3) { WAITVM(8); }
      else if (t == nt - 3) { WAITVM(4); }
      else if (t == nt - 2) { WAITVM(0); }
      __builtin_amdgcn_s_barrier();
      __builtin_amdgcn_s_setprio(1);
#pragma unroll
      for (int mt = 0; mt < 4; mt++)
#pragma unroll
        for (int n = 0; n < 4; n++)
          acc[4 + mt][n] = __builtin_amdgcn_mfma_f32_16x16x32_bf16(a[mt], b[n],
                                                                   acc[4 + mt][n], 0, 0, 0);
      __builtin_amdgcn_s_setprio(0);
      __builtin_amdgcn_s_barrier();
    } else {
      // ---- single phase: full 128x32 wave-C over K=32 ----
      bf16x8 a[8], b[2];
#pragma unroll
      for (int mt = 0; mt < 8; mt++) {
        int row = wm * 128 + mt * 16 + fr;
        a[mt] = *(const bf16x8*)(Al + row * 64 + ((fg ^ ((row >> 1) & 3)) << 4));
      }
#pragma unroll
      for (int n = 0; n < 2; n++) {
        int row = wn * 32 + n * 16 + fr;
        b[n] = *(const bf16x8*)(Bl + row * 64 + ((fg ^ ((row >> 1) & 3)) << 4));
      }
      if (dopf) { stageA(pf, t + 3); stageB(pf, t + 3); }
      if (t < nt - 3) { WAITVM(6); }
      else if (t == nt - 3) { WAITVM(3); }
      else if (t == nt - 2) { WAITVM(0); }
      __builtin_amdgcn_s_barrier();
      __builtin_amdgcn_s_setprio(1);
#pragma unroll
      for (int mt = 0; mt < 8; mt++)
#pragma unroll
        for (int n = 0; n < 2; n++)
          acc[mt][n] = __builtin_amdgcn_mfma_f32_16x16x32_bf16(a[mt], b[n],
                                                               acc[mt][n], 0, 0, 0);
      __builtin_amdgcn_s_setprio(0);
      __builtin_amdgcn_s_barrier();
    }
  }

  float* Cf = (float*)Cout + (size_t)bz * M * N;
#pragma unroll
  for (int mt = 0; mt < 8; mt++)
#pragma unroll
    for (int n = 0; n < FN; n++) {
      int col = n0 + wn * (BN / 4) + n * 16 + fr;
      float bv = (EPI == 1) ? bias[col] : 0.f;
#pragma unroll
      for (int j = 0; j < 4; j++) {
        int row = m0 + wm * 128 + mt * 16 + fg * 4 + j;
        float v = acc[mt][n][j];
        if (EPI == 1) { v += bv; v = fmaxf(v, 0.f); }
        if (EPI == 2)
          Cf[(size_t)row * N + col] = v;
        else
          ((__hip_bfloat16*)Cout)[(size_t)row * N + col] = __float2bfloat16(v);
      }
    }
}

// ---------------- V transpose: qkv v-slice -> vT[bh][64 d][2048 t] --------
__global__ __launch_bounds__(256) void k_vtrans(
    const __hip_bfloat16* __restrict__ qkv, __hip_bfloat16* __restrict__ vT) {
  __shared__ short tile[64][68];  // [t][d], pad->136B row stride
  int bh = blockIdx.x;            // b*16+h
  int tb = blockIdx.y;            // 64-row t block
  int b = bh >> 4, h = bh & 15;
  int tid = threadIdx.x;
#pragma unroll
  for (int i = 0; i < 2; i++) {
    int c = i * 256 + tid;        // 512 chunks of 8 elems
    int trow = c >> 3, seg = c & 7;
    bf16x8 v = *(const bf16x8*)((const short*)qkv +
        (size_t)(b * TS + tb * 64 + trow) * 3072 + 2048 + h * TDH + seg * 8);
    s16x4 lo = {v[0], v[1], v[2], v[3]}, hi = {v[4], v[5], v[6], v[7]};
    *(s16x4*)&tile[trow][seg * 8] = lo;
    *(s16x4*)&tile[trow][seg * 8 + 4] = hi;
  }
  __syncthreads();
#pragma unroll
  for (int i2 = 0; i2 < 2; i2++) {
    int c = i2 * 256 + tid;
    int d = c >> 3, ts = c & 7;   // output row d, t-chunk ts
    bf16x8 o;
#pragma unroll
    for (int j = 0; j < 8; j++) o[j] = tile[ts * 8 + j][d];
    *(bf16x8*)((short*)vT + (size_t)bh * TDH * TS + (size_t)d * TS +
               tb * 64 + ts * 8) = o;
  }
}

// ---------------- sliding-window attention (MFMA) --------------------------
__global__ __launch_bounds__(256) void k_attn(
    const __hip_bfloat16* __restrict__ qkv, const __hip_bfloat16* __restrict__ vT,
    const float* __restrict__ rpe, __hip_bfloat16* __restrict__ out) {
  __shared__ __align__(16) short K_lds[128 * 64];    // [jj][64k], swz
  __shared__ __align__(16) short VT_lds[64 * 128];   // [d][128jj], swz
  __shared__ __align__(16) short P_lds[4][16 * 136]; // per-wave [q][jj], pad
  __shared__ float rpe_lds[TC];
  int tid = threadIdx.x, lane = tid & 63, wave = tid >> 6;
  int fr = lane & 15, g = lane >> 4;
  int blk = blockIdx.x;           // (b*16+h)*32 + qt
  int qt = blk & 31, bh = blk >> 5;
  int h = bh & 15, b = bh >> 4;
  int t0 = qt * 64;
  const short* qg = (const short*)qkv;

  if (tid < TC) rpe_lds[tid] = rpe[h * TC + tid];

#pragma unroll
  for (int i = 0; i < 4; i++) {
    int cb = i * 256 + wave * 64;
    int c = cb + lane;
    int row = c >> 3, slot = c & 7;
    int seg = slot ^ (row & 7);
    int kr = t0 - 64 + row; if (kr < 0) kr = 0;
    GLD16(qg + ((size_t)(b * TS + kr) * 3072 + 1024 + h * TDH + seg * 8),
          (char*)K_lds + cb * 16);
  }
  const short* vg = (const short*)vT + (size_t)bh * TDH * TS;
#pragma unroll
  for (int i = 0; i < 4; i++) {
    int cb = i * 256 + wave * 64;
    int c = cb + lane;
    int row = c >> 4, slot = c & 15;
    int seg = slot ^ (row & 15);
    int tc = t0 - 64 + seg * 8; if (tc < 0) tc = 0;
    GLD16(vg + (size_t)row * TS + tc, (char*)VT_lds + cb * 16);
  }

  int qrow = t0 + wave * 16 + fr;
  const short* qptr = qg + ((size_t)(b * TS + qrow) * 3072 + h * TDH + g * 8);
  bf16x8 qf0 = *(const bf16x8*)qptr;
  bf16x8 qf1 = *(const bf16x8*)(qptr + 32);

  __syncthreads();  // drains GLD16 (vmcnt) + barrier

  f32x4 S[8] = {};
#pragma unroll
  for (int kk = 0; kk < 2; kk++) {
    bf16x8 a = kk ? qf1 : qf0;
#pragma unroll
    for (int nt = 0; nt < 8; nt++) {
      int row = nt * 16 + fr;
      int slot = (kk * 4 + g) ^ (row & 7);
      bf16x8 bfrag = *(const bf16x8*)((const char*)K_lds + row * 128 + slot * 16);
      S[nt] = __builtin_amdgcn_mfma_f32_16x16x32_bf16(a, bfrag, S[nt], 0, 0, 0);
    }
  }

  int wq = wave * 16;
#pragma unroll
  for (int r = 0; r < 4; r++) {
    int ql = g * 4 + r;
    float sc[8];
    float m = -3.4028235e38f;
#pragma unroll
    for (int nt = 0; nt < 8; nt++) {
      int jj = nt * 16 + fr;
      int d = wq + ql + 64 - jj;
      bool valid = (d >= 0) && (d < TC) && (t0 - 64 + jj >= 0);
      float v = valid ? (S[nt][r] * 0.125f + rpe_lds[d & (TC - 1)])
                      : -3.4028235e38f;
      sc[nt] = v;
      m = fmaxf(m, v);
    }
#pragma unroll
    for (int o = 1; o < 16; o <<= 1) m = fmaxf(m, __shfl_xor(m, o));
    float p[8], sum = 0.f;
#pragma unroll
    for (int nt = 0; nt < 8; nt++) { p[nt] = __expf(sc[nt] - m); sum += p[nt]; }
#pragma unroll
    for (int o = 1; o < 16; o <<= 1) sum += __shfl_xor(sum, o);
    float rs = 1.0f / sum;
#pragma unroll
    for (int nt = 0; nt < 8; nt++)
      P_lds[wave][ql * 136 + nt * 16 + fr] = f2bf(p[nt] * rs);
  }

  f32x4 O[4] = {};
#pragma unroll
  for (int kk = 0; kk < 4; kk++) {
    bf16x8 pa = *(const bf16x8*)((const char*)&P_lds[wave][0] +
                                 fr * 272 + kk * 64 + g * 16);
#pragma unroll
    for (int dt = 0; dt < 4; dt++) {
      int row = dt * 16 + fr;
      int slot = (kk * 4 + g) ^ (row & 15);
      bf16x8 vb = *(const bf16x8*)((const char*)VT_lds + row * 256 + slot * 16);
      O[dt] = __builtin_amdgcn_mfma_f32_16x16x32_bf16(pa, vb, O[dt], 0, 0, 0);
    }
  }

  size_t ob = ((size_t)(b * TS + t0 + wq + g * 4)) * TD + h * TDH;
#pragma unroll
  for (int dt = 0; dt < 4; dt++)
#pragma unroll
    for (int r = 0; r < 4; r++)
      ((short*)out)[ob + (size_t)r * TD + dt * 16 + fr] = f2bf(O[dt][r]);
}

// ---------------- LayerNorm (two-pass, fused residual + split-K sum) ------
DEVI float block_sum(float v, float* red) {
  for (int o = 32; o; o >>= 1) v += __shfl_xor(v, o);
  int wave = threadIdx.x >> 6;
  if ((threadIdx.x & 63) == 0) red[wave] = v;
  __syncthreads();
  float r = red[0] + red[1] + red[2] + red[3];
  __syncthreads();
  return r;
}

__global__ __launch_bounds__(256) void k_ln1(
    const float* __restrict__ x, const float* __restrict__ pos,
    const float* __restrict__ P0, const float* __restrict__ P1,
    const float* __restrict__ scale, const float* __restrict__ offset,
    float* __restrict__ outf, __hip_bfloat16* __restrict__ outb) {
  __shared__ float red[4];
  int row = blockIdx.x, tid = threadIdx.x;
  int t = row & (TS - 1), pr = t & (TC - 1);
  size_t base = (size_t)row * TD + tid * 4;
  f32x4 xv = *(const f32x4*)(x + base);
  f32x4 pv = *(const f32x4*)(pos + (size_t)pr * TD + tid * 4);
  f32x4 a0 = *(const f32x4*)(P0 + base);
  f32x4 a1 = *(const f32x4*)(P1 + base);
  xv = xv + pv + a0 + a1;
  float s = xv[0] + xv[1] + xv[2] + xv[3];
  s = block_sum(s, red);
  float mu = s * (1.f / TD);
  float s2 = 0.f;
  for (int j = 0; j < 4; j++) { float dlt = xv[j] - mu; s2 += dlt * dlt; }
  s2 = block_sum(s2, red);
  float rs = rsqrtf(s2 * (1.f / TD) + 1e-5f);
  f32x4 sc = *(const f32x4*)(scale + tid * 4);
  f32x4 of = *(const f32x4*)(offset + tid * 4);
  f32x4 y;
  for (int j = 0; j < 4; j++) y[j] = (xv[j] - mu) * rs * sc[j] + of[j];
  *(f32x4*)(outf + base) = y;
  s16x4 pb;
  for (int j = 0; j < 4; j++) pb[j] = f2bf(y[j]);
  *(s16x4*)((short*)outb + base) = pb;
}

__global__ __launch_bounds__(256) void k_ln2(
    const float* __restrict__ P0, const float* __restrict__ P1,
    const float* __restrict__ R, const float* __restrict__ bias,
    const float* __restrict__ scale, const float* __restrict__ offset,
    float* __restrict__ outf) {
  __shared__ float red[4];
  int row = blockIdx.x, tid = threadIdx.x;
  size_t base = (size_t)row * TD + tid * 4;
  f32x4 a0 = *(const f32x4*)(P0 + base);
  f32x4 a1 = *(const f32x4*)(P1 + base);
  f32x4 rv = *(const f32x4*)(R + base);
  f32x4 bi = *(const f32x4*)(bias + tid * 4);
  f32x4 xv = a0 + a1 + rv + bi;
  float s = xv[0] + xv[1] + xv[2] + xv[3];
  s = block_sum(s, red);
  float mu = s * (1.f / TD);
  float s2 = 0.f;
  for (int j = 0; j < 4; j++) { float dlt = xv[j] - mu; s2 += dlt * dlt; }
  s2 = block_sum(s2, red);
  float rs = rsqrtf(s2 * (1.f / TD) + 1e-5f);
  f32x4 sc = *(const f32x4*)(scale + tid * 4);
  f32x4 of = *(const f32x4*)(offset + tid * 4);
  f32x4 y;
  for (int j = 0; j < 4; j++) y[j] = (xv[j] - mu) * rs * sc[j] + of[j];
  *(f32x4*)(outf + base) = y;
}

// --------------------------------------------------------------------------
extern "C" void kernel_launch(void* const* d_in, const int* in_sizes, int n_in,
                              void* d_out, int out_size, void* d_ws, size_t ws_size,
                              hipStream_t stream) {
  const float* x    = (const float*)d_in[0];
  const float* pos  = (const float*)d_in[2];
  const float* rpe  = (const float*)d_in[3];
  const float* Wq   = (const float*)d_in[4];
  const float* Wk   = (const float*)d_in[5];
  const float* Wv   = (const float*)d_in[6];
  const float* Wo   = (const float*)d_in[7];
  const float* ln1s = (const float*)d_in[8];
  const float* ln1o = (const float*)d_in[9];
  const float* W1   = (const float*)d_in[10];
  const float* b1   = (const float*)d_in[11];
  const float* W2   = (const float*)d_in[12];
  const float* b2   = (const float*)d_in[13];
  const float* ln2s = (const float*)d_in[14];
  const float* ln2o = (const float*)d_in[15];

  char* ws = (char*)d_ws;
  const size_t MB = 1ull << 20;
  __hip_bfloat16* WqkvT = (__hip_bfloat16*)(ws + 0 * MB);   // 6 MB
  __hip_bfloat16* WoT   = (__hip_bfloat16*)(ws + 6 * MB);   // 2 MB
  __hip_bfloat16* W1T   = (__hip_bfloat16*)(ws + 8 * MB);   // 8 MB
  __hip_bfloat16* W2T   = (__hip_bfloat16*)(ws + 16 * MB);  // 8 MB
  __hip_bfloat16* hB    = (__hip_bfloat16*)(ws + 24 * MB);  // 8 MB (dead after QKV)
  __hip_bfloat16* qkv   = (__hip_bfloat16*)(ws + 32 * MB);  // 24 MB (dead after attn)
  __hip_bfloat16* aoB   = (__hip_bfloat16*)(ws + 56 * MB);  // 8 MB (dead after Wo)
  float*          oF2   = (float*)(ws + 64 * MB);           // 32 MB (dead after ln1)
  float*          atF   = (float*)(ws + 96 * MB);           // 16 MB
  __hip_bfloat16* atB   = (__hip_bfloat16*)(ws + 24 * MB);  // 8 MB (aliases hB)
  __hip_bfloat16* ff1   = (__hip_bfloat16*)(ws + 32 * MB);  // 32 MB (aliases qkv+aoB)
  float*          ff2   = (float*)(ws + 64 * MB);           // 32 MB (aliases oF2)
  __hip_bfloat16* vTb   = (__hip_bfloat16*)(ws + 112 * MB); // 8 MB (dead after attn)
  // high-water: 120 MB

  dim3 blk(256), blk5(512);

  // weight transposes + addpos fused (12288 transpose blocks + 4096 addpos)
  k_trans_all<<<16384, blk, 0, stream>>>(Wq, Wk, Wv, Wo, W1, W2,
                                         WqkvT, WoT, W1T, W2T, x, pos, hB);

  // QKV fused: (4096 x 1024) * (3072 x 1024)^T -> bf16 qkv
  k_gemm8<256, 0><<<dim3(TM / 256, 3072 / 256, 1), blk5, 0, stream>>>(
      hB, WqkvT, qkv, nullptr, TM, 3072, TD, TD, TD);

  k_vtrans<<<dim3(TB * TH, TS / 64), blk, 0, stream>>>(qkv, vTb);
  k_attn<<<TB * TH * (TS / 64), blk, 0, stream>>>(qkv, vTb, rpe, aoB);

  // Wo: BN=128, split-K=2 -> two f32 partials (grid 16x8x2 = 256 blocks)
  k_gemm8<128, 2><<<dim3(TM / 256, TD / 128, 2), blk5, 0, stream>>>(
      aoB, WoT, oF2, nullptr, TM, TD, TD / 2, TD, TD);

  k_ln1<<<TM, blk, 0, stream>>>(x, pos, oF2, oF2 + (size_t)TM * TD, ln1s, ln1o, atF, atB);

  // FFN1: bias+relu -> bf16 (grid 16x16 = 256 blocks)
  k_gemm8<256, 1><<<dim3(TM / 256, TFF / 256, 1), blk5, 0, stream>>>(
      atB, W1T, ff1, b1, TM, TFF, TD, TD, TD);

  // FFN2: BN=128, split-K=2 -> two f32 partials (grid 16x8x2 = 256 blocks)
  k_gemm8<128, 2><<<dim3(TM / 256, TD / 128, 2), blk5, 0, stream>>>(
      ff1, W2T, ff2, nullptr, TM, TD, TFF / 2, TFF, TFF);

  k_ln2<<<TM, blk, 0, stream>>>(ff2, ff2 + (size_t)TM * TD, atF, b2, ln2s, ln2o,
                                (float*)d_out);
}

// Round 9
// 197.916 us; speedup vs baseline: 1.2061x; 1.0386x over previous
//
#include <hip/hip_runtime.h>
#include <hip/hip_bf16.h>

#define DEVI static __device__ __forceinline__

typedef __attribute__((ext_vector_type(4))) float f32x4;
typedef __attribute__((ext_vector_type(8))) short bf16x8;
typedef __attribute__((ext_vector_type(4))) short s16x4;

constexpr int TB  = 2;      // batch
constexpr int TS  = 2048;   // seq len
constexpr int TD  = 1024;   // model dim
constexpr int TH  = 16;     // heads
constexpr int TDH = 64;     // head dim
constexpr int TC  = 64;     // window size
constexpr int TFF = 4096;   // ffn dim
constexpr int TM  = TB * TS;  // 4096 rows

DEVI float bf2f(short s) {
  return __builtin_bit_cast(float, (unsigned)((unsigned short)s) << 16);
}
DEVI short f2bf(float f) {
  return __builtin_bit_cast(short, __float2bfloat16(f));
}

// async global->LDS, 16B per lane, dest = wave-uniform base + lane*16
#define GLD16(gp, lp)                                              \
  __builtin_amdgcn_global_load_lds(                                \
      (const __attribute__((address_space(1))) void*)(gp),         \
      (__attribute__((address_space(3))) void*)(lp), 16, 0, 0)

// counted vmcnt wait (N = max loads allowed outstanding), compiler-fenced
#define WAITVM(N) asm volatile("s_waitcnt vmcnt(" #N ")" ::: "memory")

// ---------------- weight transposes + addpos in ONE dispatch --------------
__global__ __launch_bounds__(256) void k_trans_all(
    const float* __restrict__ Wq, const float* __restrict__ Wk,
    const float* __restrict__ Wv, const float* __restrict__ Wo,
    const float* __restrict__ W1, const float* __restrict__ W2,
    __hip_bfloat16* __restrict__ WqkvT, __hip_bfloat16* __restrict__ WoT,
    __hip_bfloat16* __restrict__ W1T, __hip_bfloat16* __restrict__ W2T,
    const float* __restrict__ x, const float* __restrict__ pos,
    __hip_bfloat16* __restrict__ hb) {
  int bid = blockIdx.x;
  if (bid >= 12288) {                    // addpos: h = x + pos[t % C]
    int i = (bid - 12288) * 256 + threadIdx.x;
    int e = i * 4;
    int d = e & (TD - 1);
    int t = (e / TD) & (TS - 1);
    f32x4 xv = *(const f32x4*)(x + e);
    f32x4 pv = *(const f32x4*)(pos + (size_t)(t & (TC - 1)) * TD + d);
    s16x4 hb4;
    for (int j = 0; j < 4; j++) hb4[j] = f2bf(xv[j] + pv[j]);
    *(s16x4*)((short*)hb + e) = hb4;
    return;
  }
  __shared__ float tile[32][33];
  const float* src; __hip_bfloat16* dst;
  int K, N, n0, k0;
  if (bid < 4096) {                      // Wq,Wk,Wv,Wo : 1024x1024 each
    int m = bid >> 10, t = bid & 1023;
    src = (m == 0) ? Wq : (m == 1) ? Wk : (m == 2) ? Wv : Wo;
    dst = (m == 3) ? WoT : WqkvT + (size_t)m * TD * TD;
    K = TD; N = TD; n0 = (t & 31) * 32; k0 = (t >> 5) * 32;
  } else if (bid < 8192) {               // W1 : 1024x4096
    int t = bid - 4096;
    src = W1; dst = W1T; K = TD; N = TFF;
    n0 = (t & 127) * 32; k0 = (t >> 7) * 32;
  } else {                               // W2 : 4096x1024
    int t = bid - 8192;
    src = W2; dst = W2T; K = TFF; N = TD;
    n0 = (t & 31) * 32; k0 = (t >> 5) * 32;
  }
  int tx = threadIdx.x & 31, ty = threadIdx.x >> 5;  // 32 x 8
  for (int i = 0; i < 32; i += 8)
    tile[ty + i][tx] = src[(size_t)(k0 + ty + i) * N + n0 + tx];
  __syncthreads();
  for (int i = 0; i < 32; i += 8)
    dst[(size_t)(n0 + ty + i) * K + k0 + tx] = __float2bfloat16(tile[tx][ty + i]);
}

// ---------------- bf16 MFMA GEMM: r6/r8-proven 2-phase, ring-4, T1 --------
// C = A(MxK) * BT(NxK)^T.  BM=256, BK=32, 512 thr = 8 waves (2M x 4N).
// Ring-4 LDS; counted vmcnt keeps 2 tiles of loads in flight across
// barriers; T1 XCD-aware bijective remap; T5 setprio.  Swizzle: LDS slot s
// of row r holds k-octet s^((r>>1)&3) (0-conflict, measured r4-r8).
// EPI: 0 = store bf16, 1 = bias+relu bf16, 2 = bf16 split-K partial at
// z*M*N (bf16 partial rounding ~2e-3, well inside threshold).
template <int BN, int EPI>
__global__ __launch_bounds__(512, 2) void k_gemm8(
    const __hip_bfloat16* __restrict__ A, const __hip_bfloat16* __restrict__ BT,
    void* __restrict__ Cout, const float* __restrict__ bias,
    int M, int N, int K, int lda, int ldb) {
  constexpr int BM = 256, BK = 32;
  constexpr int FN = BN / 64;                  // n-frags per wave: 4 or 2
  __shared__ __align__(16) short As[4][BM * BK];  // 4 x 16 KB
  __shared__ __align__(16) short Bs[4][BN * BK];  // 4 x (16 | 8) KB
  int tid = threadIdx.x, lane = tid & 63, wave = tid >> 6;
  int wm = wave >> 2, wn = wave & 3;           // 2 x 4 wave grid
  int fr = lane & 15, fg = lane >> 4;

  // ---- T1: XCD-aware bijective remap (nb % 8 == 0 for all our grids) ----
  int bx, by, bz;
  {
    int gx = gridDim.x, gy = gridDim.y;
    int nb = gx * gy * gridDim.z;
    int phys = blockIdx.x + gx * (blockIdx.y + gy * blockIdx.z);
    int chunk = nb >> 3;
    int logical = (phys & 7) * chunk + (phys >> 3);
    int perz = gx * gy;
    bz = logical / perz;
    int l2 = logical - bz * perz;
    int g = l2 / (8 * gy);
    int r = l2 - g * 8 * gy;
    by = r >> 3;
    bx = g * 8 + (r & 7);
  }
  int m0 = bx * BM, n0 = by * BN;
  size_t koff = (size_t)bz * K;
  const short* Ab = (const short*)A + koff;
  const short* Bb = (const short*)BT + koff;

  int r0 = tid >> 2, s0 = (tid & 3) ^ ((r0 >> 1) & 3);
  int r1 = 128 + r0, s1 = (tid & 3) ^ ((r1 >> 1) & 3);
  const short* pA0 = Ab + (size_t)(m0 + r0) * lda + s0 * 8;
  const short* pA1 = Ab + (size_t)(m0 + r1) * lda + s1 * 8;
  const short* pB0 = Bb + (size_t)(n0 + r0) * ldb + s0 * 8;
  const short* pB1 = (BN == 256) ? Bb + (size_t)(n0 + r1) * ldb + s1 * 8 : pB0;
  int dst0 = (wave * 64) * 16;                 // LDS byte offsets
  int dst1 = (512 + wave * 64) * 16;

  auto stageA = [&](int d, int T) {
    GLD16(pA0 + T * BK, (char*)&As[d][0] + dst0);
    GLD16(pA1 + T * BK, (char*)&As[d][0] + dst1);
  };
  auto stageB = [&](int d, int T) {
    GLD16(pB0 + T * BK, (char*)&Bs[d][0] + dst0);
    if constexpr (BN == 256) GLD16(pB1 + T * BK, (char*)&Bs[d][0] + dst1);
  };

  f32x4 acc[8][FN];
#pragma unroll
  for (int m = 0; m < 8; m++)
#pragma unroll
    for (int n = 0; n < FN; n++) acc[m][n] = f32x4{0.f, 0.f, 0.f, 0.f};

  const int nt = K / BK;  // >= 16 for all shapes used
  stageA(0, 0); stageB(0, 0);
  stageA(1, 1); stageB(1, 1);
  stageA(2, 2); stageB(2, 2);
  if (BN == 256) { WAITVM(8); } else { WAITVM(6); }  // tile 0 landed; 1,2 fly
  __builtin_amdgcn_s_barrier();

  for (int t = 0; t < nt; t++) {
    int d = t & 3, pf = (t + 3) & 3;
    bool dopf = (t + 3) < nt;
    const char* Al = (const char*)&As[d][0];
    const char* Bl = (const char*)&Bs[d][0];
    if constexpr (BN == 256) {
      bf16x8 a[4], b[4];
      // ---- phase 0: m-half 0, load B frags (reused in phase 1) ----
#pragma unroll
      for (int mt = 0; mt < 4; mt++) {
        int row = wm * 128 + mt * 16 + fr;
        a[mt] = *(const bf16x8*)(Al + row * 64 + ((fg ^ ((row >> 1) & 3)) << 4));
      }
#pragma unroll
      for (int n = 0; n < 4; n++) {
        int row = wn * 64 + n * 16 + fr;
        b[n] = *(const bf16x8*)(Bl + row * 64 + ((fg ^ ((row >> 1) & 3)) << 4));
      }
      if (dopf) stageA(pf, t + 3);
      __builtin_amdgcn_s_barrier();
      __builtin_amdgcn_s_setprio(1);
#pragma unroll
      for (int mt = 0; mt < 4; mt++)
#pragma unroll
        for (int n = 0; n < 4; n++)
          acc[mt][n] = __builtin_amdgcn_mfma_f32_16x16x32_bf16(a[mt], b[n],
                                                               acc[mt][n], 0, 0, 0);
      __builtin_amdgcn_s_setprio(0);
      __builtin_amdgcn_s_barrier();
      // ---- phase 1: m-half 1 ----
#pragma unroll
      for (int mt = 0; mt < 4; mt++) {
        int row = wm * 128 + 64 + mt * 16 + fr;
        a[mt] = *(const bf16x8*)(Al + row * 64 + ((fg ^ ((row >> 1) & 3)) << 4));
      }
      if (dopf) stageB(pf, t + 3);
      if (t < nt - 3) { WAITVM(8); }
      else if (t == nt - 3) { WAITVM(4); }
      else if (t == nt - 2) { WAITVM(0); }
      __builtin_amdgcn_s_barrier();
      __builtin_amdgcn_s_setprio(1);
#pragma unroll
      for (int mt = 0; mt < 4; mt++)
#pragma unroll
        for (int n = 0; n < 4; n++)
          acc[4 + mt][n] = __builtin_amdgcn_mfma_f32_16x16x32_bf16(a[mt], b[n],
                                                                   acc[4 + mt][n], 0, 0, 0);
      __builtin_amdgcn_s_setprio(0);
      __builtin_amdgcn_s_barrier();
    } else {
      // ---- single phase: full 128x32 wave-C over K=32 ----
      bf16x8 a[8], b[2];
#pragma unroll
      for (int mt = 0; mt < 8; mt++) {
        int row = wm * 128 + mt * 16 + fr;
        a[mt] = *(const bf16x8*)(Al + row * 64 + ((fg ^ ((row >> 1) & 3)) << 4));
      }
#pragma unroll
      for (int n = 0; n < 2; n++) {
        int row = wn * 32 + n * 16 + fr;
        b[n] = *(const bf16x8*)(Bl + row * 64 + ((fg ^ ((row >> 1) & 3)) << 4));
      }
      if (dopf) { stageA(pf, t + 3); stageB(pf, t + 3); }
      if (t < nt - 3) { WAITVM(6); }
      else if (t == nt - 3) { WAITVM(3); }
      else if (t == nt - 2) { WAITVM(0); }
      __builtin_amdgcn_s_barrier();
      __builtin_amdgcn_s_setprio(1);
#pragma unroll
      for (int mt = 0; mt < 8; mt++)
#pragma unroll
        for (int n = 0; n < 2; n++)
          acc[mt][n] = __builtin_amdgcn_mfma_f32_16x16x32_bf16(a[mt], b[n],
                                                               acc[mt][n], 0, 0, 0);
      __builtin_amdgcn_s_setprio(0);
      __builtin_amdgcn_s_barrier();
    }
  }

#pragma unroll
  for (int mt = 0; mt < 8; mt++)
#pragma unroll
    for (int n = 0; n < FN; n++) {
      int col = n0 + wn * (BN / 4) + n * 16 + fr;
      float bv = (EPI == 1) ? bias[col] : 0.f;
#pragma unroll
      for (int j = 0; j < 4; j++) {
        int row = m0 + wm * 128 + mt * 16 + fg * 4 + j;
        float v = acc[mt][n][j];
        if (EPI == 1) { v += bv; v = fmaxf(v, 0.f); }
        if (EPI == 2)
          ((__hip_bfloat16*)Cout)[(size_t)bz * M * N + (size_t)row * N + col] =
              __float2bfloat16(v);
        else
          ((__hip_bfloat16*)Cout)[(size_t)row * N + col] = __float2bfloat16(v);
      }
    }
}

// ---------------- V transpose: qkv v-slice -> vT[bh][64 d][2048 t] --------
__global__ __launch_bounds__(256) void k_vtrans(
    const __hip_bfloat16* __restrict__ qkv, __hip_bfloat16* __restrict__ vT) {
  __shared__ short tile[64][68];  // [t][d], pad->136B row stride
  int bh = blockIdx.x;            // b*16+h
  int tb = blockIdx.y;            // 64-row t block
  int b = bh >> 4, h = bh & 15;
  int tid = threadIdx.x;
#pragma unroll
  for (int i = 0; i < 2; i++) {
    int c = i * 256 + tid;        // 512 chunks of 8 elems
    int trow = c >> 3, seg = c & 7;
    bf16x8 v = *(const bf16x8*)((const short*)qkv +
        (size_t)(b * TS + tb * 64 + trow) * 3072 + 2048 + h * TDH + seg * 8);
    s16x4 lo = {v[0], v[1], v[2], v[3]}, hi = {v[4], v[5], v[6], v[7]};
    *(s16x4*)&tile[trow][seg * 8] = lo;
    *(s16x4*)&tile[trow][seg * 8 + 4] = hi;
  }
  __syncthreads();
#pragma unroll
  for (int i2 = 0; i2 < 2; i2++) {
    int c = i2 * 256 + tid;
    int d = c >> 3, ts = c & 7;   // output row d, t-chunk ts
    bf16x8 o;
#pragma unroll
    for (int j = 0; j < 8; j++) o[j] = tile[ts * 8 + j][d];
    *(bf16x8*)((short*)vT + (size_t)bh * TDH * TS + (size_t)d * TS +
               tb * 64 + ts * 8) = o;
  }
}

// ---------------- sliding-window attention (MFMA) --------------------------
__global__ __launch_bounds__(256) void k_attn(
    const __hip_bfloat16* __restrict__ qkv, const __hip_bfloat16* __restrict__ vT,
    const float* __restrict__ rpe, __hip_bfloat16* __restrict__ out) {
  __shared__ __align__(16) short K_lds[128 * 64];    // [jj][64k], swz
  __shared__ __align__(16) short VT_lds[64 * 128];   // [d][128jj], swz
  __shared__ __align__(16) short P_lds[4][16 * 136]; // per-wave [q][jj], pad
  __shared__ float rpe_lds[TC];
  int tid = threadIdx.x, lane = tid & 63, wave = tid >> 6;
  int fr = lane & 15, g = lane >> 4;
  int blk = blockIdx.x;           // (b*16+h)*32 + qt
  int qt = blk & 31, bh = blk >> 5;
  int h = bh & 15, b = bh >> 4;
  int t0 = qt * 64;
  const short* qg = (const short*)qkv;

  if (tid < TC) rpe_lds[tid] = rpe[h * TC + tid];

#pragma unroll
  for (int i = 0; i < 4; i++) {
    int cb = i * 256 + wave * 64;
    int c = cb + lane;
    int row = c >> 3, slot = c & 7;
    int seg = slot ^ (row & 7);
    int kr = t0 - 64 + row; if (kr < 0) kr = 0;
    GLD16(qg + ((size_t)(b * TS + kr) * 3072 + 1024 + h * TDH + seg * 8),
          (char*)K_lds + cb * 16);
  }
  const short* vg = (const short*)vT + (size_t)bh * TDH * TS;
#pragma unroll
  for (int i = 0; i < 4; i++) {
    int cb = i * 256 + wave * 64;
    int c = cb + lane;
    int row = c >> 4, slot = c & 15;
    int seg = slot ^ (row & 15);
    int tc = t0 - 64 + seg * 8; if (tc < 0) tc = 0;
    GLD16(vg + (size_t)row * TS + tc, (char*)VT_lds + cb * 16);
  }

  int qrow = t0 + wave * 16 + fr;
  const short* qptr = qg + ((size_t)(b * TS + qrow) * 3072 + h * TDH + g * 8);
  bf16x8 qf0 = *(const bf16x8*)qptr;
  bf16x8 qf1 = *(const bf16x8*)(qptr + 32);

  __syncthreads();  // drains GLD16 (vmcnt) + barrier

  f32x4 S[8] = {};
#pragma unroll
  for (int kk = 0; kk < 2; kk++) {
    bf16x8 a = kk ? qf1 : qf0;
#pragma unroll
    for (int nt = 0; nt < 8; nt++) {
      int row = nt * 16 + fr;
      int slot = (kk * 4 + g) ^ (row & 7);
      bf16x8 bfrag = *(const bf16x8*)((const char*)K_lds + row * 128 + slot * 16);
      S[nt] = __builtin_amdgcn_mfma_f32_16x16x32_bf16(a, bfrag, S[nt], 0, 0, 0);
    }
  }

  int wq = wave * 16;
#pragma unroll
  for (int r = 0; r < 4; r++) {
    int ql = g * 4 + r;
    float sc[8];
    float m = -3.4028235e38f;
#pragma unroll
    for (int nt = 0; nt < 8; nt++) {
      int jj = nt * 16 + fr;
      int d = wq + ql + 64 - jj;
      bool valid = (d >= 0) && (d < TC) && (t0 - 64 + jj >= 0);
      float v = valid ? (S[nt][r] * 0.125f + rpe_lds[d & (TC - 1)])
                      : -3.4028235e38f;
      sc[nt] = v;
      m = fmaxf(m, v);
    }
#pragma unroll
    for (int o = 1; o < 16; o <<= 1) m = fmaxf(m, __shfl_xor(m, o));
    float p[8], sum = 0.f;
#pragma unroll
    for (int nt = 0; nt < 8; nt++) { p[nt] = __expf(sc[nt] - m); sum += p[nt]; }
#pragma unroll
    for (int o = 1; o < 16; o <<= 1) sum += __shfl_xor(sum, o);
    float rs = 1.0f / sum;
#pragma unroll
    for (int nt = 0; nt < 8; nt++)
      P_lds[wave][ql * 136 + nt * 16 + fr] = f2bf(p[nt] * rs);
  }

  f32x4 O[4] = {};
#pragma unroll
  for (int kk = 0; kk < 4; kk++) {
    bf16x8 pa = *(const bf16x8*)((const char*)&P_lds[wave][0] +
                                 fr * 272 + kk * 64 + g * 16);
#pragma unroll
    for (int dt = 0; dt < 4; dt++) {
      int row = dt * 16 + fr;
      int slot = (kk * 4 + g) ^ (row & 15);
      bf16x8 vb = *(const bf16x8*)((const char*)VT_lds + row * 256 + slot * 16);
      O[dt] = __builtin_amdgcn_mfma_f32_16x16x32_bf16(pa, vb, O[dt], 0, 0, 0);
    }
  }

  size_t ob = ((size_t)(b * TS + t0 + wq + g * 4)) * TD + h * TDH;
#pragma unroll
  for (int dt = 0; dt < 4; dt++)
#pragma unroll
    for (int r = 0; r < 4; r++)
      ((short*)out)[ob + (size_t)r * TD + dt * 16 + fr] = f2bf(O[dt][r]);
}

// ---------------- LayerNorm (two-pass, fused residual + split-K sum) ------
DEVI float block_sum(float v, float* red) {
  for (int o = 32; o; o >>= 1) v += __shfl_xor(v, o);
  int wave = threadIdx.x >> 6;
  if ((threadIdx.x & 63) == 0) red[wave] = v;
  __syncthreads();
  float r = red[0] + red[1] + red[2] + red[3];
  __syncthreads();
  return r;
}

// ln1: in = h (bf16) + P0 + P1 (bf16 split-K partials); out f32 + bf16.
// hB aliases outb: each thread reads its own 4 elems before writing them.
__global__ __launch_bounds__(256) void k_ln1(
    const __hip_bfloat16* __restrict__ hB, const __hip_bfloat16* __restrict__ P0,
    const __hip_bfloat16* __restrict__ P1, const float* __restrict__ scale,
    const float* __restrict__ offset, float* __restrict__ outf,
    __hip_bfloat16* __restrict__ outb) {
  __shared__ float red[4];
  int row = blockIdx.x, tid = threadIdx.x;
  size_t base = (size_t)row * TD + tid * 4;
  s16x4 hv = *(const s16x4*)((const short*)hB + base);
  s16x4 a0 = *(const s16x4*)((const short*)P0 + base);
  s16x4 a1 = *(const s16x4*)((const short*)P1 + base);
  f32x4 xv;
  for (int j = 0; j < 4; j++) xv[j] = bf2f(hv[j]) + bf2f(a0[j]) + bf2f(a1[j]);
  float s = xv[0] + xv[1] + xv[2] + xv[3];
  s = block_sum(s, red);
  float mu = s * (1.f / TD);
  float s2 = 0.f;
  for (int j = 0; j < 4; j++) { float dlt = xv[j] - mu; s2 += dlt * dlt; }
  s2 = block_sum(s2, red);
  float rs = rsqrtf(s2 * (1.f / TD) + 1e-5f);
  f32x4 sc = *(const f32x4*)(scale + tid * 4);
  f32x4 of = *(const f32x4*)(offset + tid * 4);
  f32x4 y;
  for (int j = 0; j < 4; j++) y[j] = (xv[j] - mu) * rs * sc[j] + of[j];
  *(f32x4*)(outf + base) = y;
  s16x4 pb;
  for (int j = 0; j < 4; j++) pb[j] = f2bf(y[j]);
  *(s16x4*)((short*)outb + base) = pb;
}

// ln2: in = P0 + P1 (bf16 partials) + R (f32) + bias; out f32 (d_out)
__global__ __launch_bounds__(256) void k_ln2(
    const __hip_bfloat16* __restrict__ P0, const __hip_bfloat16* __restrict__ P1,
    const float* __restrict__ R, const float* __restrict__ bias,
    const float* __restrict__ scale, const float* __restrict__ offset,
    float* __restrict__ outf) {
  __shared__ float red[4];
  int row = blockIdx.x, tid = threadIdx.x;
  size_t base = (size_t)row * TD + tid * 4;
  s16x4 a0 = *(const s16x4*)((const short*)P0 + base);
  s16x4 a1 = *(const s16x4*)((const short*)P1 + base);
  f32x4 rv = *(const f32x4*)(R + base);
  f32x4 bi = *(const f32x4*)(bias + tid * 4);
  f32x4 xv;
  for (int j = 0; j < 4; j++) xv[j] = bf2f(a0[j]) + bf2f(a1[j]) + rv[j] + bi[j];
  float s = xv[0] + xv[1] + xv[2] + xv[3];
  s = block_sum(s, red);
  float mu = s * (1.f / TD);
  float s2 = 0.f;
  for (int j = 0; j < 4; j++) { float dlt = xv[j] - mu; s2 += dlt * dlt; }
  s2 = block_sum(s2, red);
  float rs = rsqrtf(s2 * (1.f / TD) + 1e-5f);
  f32x4 sc = *(const f32x4*)(scale + tid * 4);
  f32x4 of = *(const f32x4*)(offset + tid * 4);
  f32x4 y;
  for (int j = 0; j < 4; j++) y[j] = (xv[j] - mu) * rs * sc[j] + of[j];
  *(f32x4*)(outf + base) = y;
}

// --------------------------------------------------------------------------
extern "C" void kernel_launch(void* const* d_in, const int* in_sizes, int n_in,
                              void* d_out, int out_size, void* d_ws, size_t ws_size,
                              hipStream_t stream) {
  const float* x    = (const float*)d_in[0];
  const float* pos  = (const float*)d_in[2];
  const float* rpe  = (const float*)d_in[3];
  const float* Wq   = (const float*)d_in[4];
  const float* Wk   = (const float*)d_in[5];
  const float* Wv   = (const float*)d_in[6];
  const float* Wo   = (const float*)d_in[7];
  const float* ln1s = (const float*)d_in[8];
  const float* ln1o = (const float*)d_in[9];
  const float* W1   = (const float*)d_in[10];
  const float* b1   = (const float*)d_in[11];
  const float* W2   = (const float*)d_in[12];
  const float* b2   = (const float*)d_in[13];
  const float* ln2s = (const float*)d_in[14];
  const float* ln2o = (const float*)d_in[15];

  char* ws = (char*)d_ws;
  const size_t MB = 1ull << 20;
  __hip_bfloat16* WqkvT = (__hip_bfloat16*)(ws + 0 * MB);   // 6 MB
  __hip_bfloat16* WoT   = (__hip_bfloat16*)(ws + 6 * MB);   // 2 MB
  __hip_bfloat16* W1T   = (__hip_bfloat16*)(ws + 8 * MB);   // 8 MB
  __hip_bfloat16* W2T   = (__hip_bfloat16*)(ws + 16 * MB);  // 8 MB
  __hip_bfloat16* hB    = (__hip_bfloat16*)(ws + 24 * MB);  // 8 MB (h until ln1)
  __hip_bfloat16* qkv   = (__hip_bfloat16*)(ws + 32 * MB);  // 24 MB (dead after attn)
  __hip_bfloat16* aoB   = (__hip_bfloat16*)(ws + 56 * MB);  // 8 MB (dead after Wo)
  __hip_bfloat16* oB2   = (__hip_bfloat16*)(ws + 64 * MB);  // 16 MB, 2 bf16 partials
  float*          atF   = (float*)(ws + 96 * MB);           // 16 MB
  __hip_bfloat16* atB   = (__hip_bfloat16*)(ws + 24 * MB);  // 8 MB (aliases hB; ln1 RMW-safe)
  __hip_bfloat16* ff1   = (__hip_bfloat16*)(ws + 32 * MB);  // 32 MB (aliases qkv+aoB)
  __hip_bfloat16* ff2   = (__hip_bfloat16*)(ws + 64 * MB);  // 16 MB (aliases oB2)
  __hip_bfloat16* vTb   = (__hip_bfloat16*)(ws + 112 * MB); // 8 MB (dead after attn)
  // high-water: 120 MB

  dim3 blk(256), blk5(512);

  // weight transposes + addpos fused (12288 transpose blocks + 4096 addpos)
  k_trans_all<<<16384, blk, 0, stream>>>(Wq, Wk, Wv, Wo, W1, W2,
                                         WqkvT, WoT, W1T, W2T, x, pos, hB);

  // QKV fused: (4096 x 1024) * (3072 x 1024)^T -> bf16 qkv
  k_gemm8<256, 0><<<dim3(TM / 256, 3072 / 256, 1), blk5, 0, stream>>>(
      hB, WqkvT, qkv, nullptr, TM, 3072, TD, TD, TD);

  k_vtrans<<<dim3(TB * TH, TS / 64), blk, 0, stream>>>(qkv, vTb);
  k_attn<<<TB * TH * (TS / 64), blk, 0, stream>>>(qkv, vTb, rpe, aoB);

  // Wo: BN=128, split-K=2 -> two bf16 partials (grid 16x8x2 = 256 blocks)
  k_gemm8<128, 2><<<dim3(TM / 256, TD / 128, 2), blk5, 0, stream>>>(
      aoB, WoT, oB2, nullptr, TM, TD, TD / 2, TD, TD);

  k_ln1<<<TM, blk, 0, stream>>>(hB, oB2, oB2 + (size_t)TM * TD, ln1s, ln1o,
                                atF, atB);

  // FFN1: bias+relu -> bf16 (grid 16x16 = 256 blocks)
  k_gemm8<256, 1><<<dim3(TM / 256, TFF / 256, 1), blk5, 0, stream>>>(
      atB, W1T, ff1, b1, TM, TFF, TD, TD, TD);

  // FFN2: BN=128, split-K=2 -> two bf16 partials (grid 16x8x2 = 256 blocks)
  k_gemm8<128, 2><<<dim3(TM / 256, TD / 128, 2), blk5, 0, stream>>>(
      ff1, W2T, ff2, nullptr, TM, TD, TFF / 2, TFF, TFF);

  k_ln2<<<TM, blk, 0, stream>>>(ff2, ff2 + (size_t)TM * TD, atF, b2, ln2s, ln2o,
                                (float*)d_out);
}

// Round 10
// 189.755 us; speedup vs baseline: 1.2580x; 1.0430x over previous
//
#include <hip/hip_runtime.h>
#include <hip/hip_bf16.h>

#define DEVI static __device__ __forceinline__

typedef __attribute__((ext_vector_type(4))) float f32x4;
typedef __attribute__((ext_vector_type(8))) short bf16x8;
typedef __attribute__((ext_vector_type(4))) short s16x4;

constexpr int TB  = 2;      // batch
constexpr int TS  = 2048;   // seq len
constexpr int TD  = 1024;   // model dim
constexpr int TH  = 16;     // heads
constexpr int TDH = 64;     // head dim
constexpr int TC  = 64;     // window size
constexpr int TFF = 4096;   // ffn dim
constexpr int TM  = TB * TS;  // 4096 rows

DEVI float bf2f(short s) {
  return __builtin_bit_cast(float, (unsigned)((unsigned short)s) << 16);
}
DEVI short f2bf(float f) {
  return __builtin_bit_cast(short, __float2bfloat16(f));
}

// async global->LDS, 16B per lane, dest = wave-uniform base + lane*16
#define GLD16(gp, lp)                                              \
  __builtin_amdgcn_global_load_lds(                                \
      (const __attribute__((address_space(1))) void*)(gp),         \
      (__attribute__((address_space(3))) void*)(lp), 16, 0, 0)

// counted vmcnt wait (N = max loads allowed outstanding), compiler-fenced
#define WAITVM(N) asm volatile("s_waitcnt vmcnt(" #N ")" ::: "memory")

// T1 XCD-aware bijective remap (requires nb%8==0, gx%8==0; all our grids)
DEVI void xcd_remap(int& bx, int& by, int& bz) {
  int gx = gridDim.x, gy = gridDim.y;
  int nb = gx * gy * gridDim.z;
  int phys = blockIdx.x + gx * (blockIdx.y + gy * blockIdx.z);
  int chunk = nb >> 3;
  int logical = (phys & 7) * chunk + (phys >> 3);
  int perz = gx * gy;
  bz = logical / perz;
  int l2 = logical - bz * perz;
  int g = l2 / (8 * gy);
  int r = l2 - g * 8 * gy;
  by = r >> 3;
  bx = g * 8 + (r & 7);
}

// ---------------- weight transposes + addpos in ONE dispatch --------------
__global__ __launch_bounds__(256) void k_trans_all(
    const float* __restrict__ Wq, const float* __restrict__ Wk,
    const float* __restrict__ Wv, const float* __restrict__ Wo,
    const float* __restrict__ W1, const float* __restrict__ W2,
    __hip_bfloat16* __restrict__ WqkvT, __hip_bfloat16* __restrict__ WoT,
    __hip_bfloat16* __restrict__ W1T, __hip_bfloat16* __restrict__ W2T,
    const float* __restrict__ x, const float* __restrict__ pos,
    __hip_bfloat16* __restrict__ hb) {
  int bid = blockIdx.x;
  if (bid >= 12288) {                    // addpos: h = x + pos[t % C]
    int i = (bid - 12288) * 256 + threadIdx.x;
    int e = i * 4;
    int d = e & (TD - 1);
    int t = (e / TD) & (TS - 1);
    f32x4 xv = *(const f32x4*)(x + e);
    f32x4 pv = *(const f32x4*)(pos + (size_t)(t & (TC - 1)) * TD + d);
    s16x4 hb4;
    for (int j = 0; j < 4; j++) hb4[j] = f2bf(xv[j] + pv[j]);
    *(s16x4*)((short*)hb + e) = hb4;
    return;
  }
  __shared__ float tile[32][33];
  const float* src; __hip_bfloat16* dst;
  int K, N, n0, k0;
  if (bid < 4096) {                      // Wq,Wk,Wv,Wo : 1024x1024 each
    int m = bid >> 10, t = bid & 1023;
    src = (m == 0) ? Wq : (m == 1) ? Wk : (m == 2) ? Wv : Wo;
    dst = (m == 3) ? WoT : WqkvT + (size_t)m * TD * TD;
    K = TD; N = TD; n0 = (t & 31) * 32; k0 = (t >> 5) * 32;
  } else if (bid < 8192) {               // W1 : 1024x4096
    int t = bid - 4096;
    src = W1; dst = W1T; K = TD; N = TFF;
    n0 = (t & 127) * 32; k0 = (t >> 7) * 32;
  } else {                               // W2 : 4096x1024
    int t = bid - 8192;
    src = W2; dst = W2T; K = TFF; N = TD;
    n0 = (t & 31) * 32; k0 = (t >> 5) * 32;
  }
  int tx = threadIdx.x & 31, ty = threadIdx.x >> 5;  // 32 x 8
  for (int i = 0; i < 32; i += 8)
    tile[ty + i][tx] = src[(size_t)(k0 + ty + i) * N + n0 + tx];
  __syncthreads();
  for (int i = 0; i < 32; i += 8)
    dst[(size_t)(n0 + ty + i) * K + k0 + tx] = __float2bfloat16(tile[tx][ty + i]);
}

// ---------------- m201-template GEMM: BK=64, half-tiles, 4 quadrant phases -
// C = A(MxK)*BT(NxK)^T.  BM=BN=256, BK=64, 512 thr = 8 waves (2M x 4N),
// per-wave C = 128x64.  LDS: 2 dbuf x 2 half x [128][64] for A and B
// (128 KiB).  Wave wm reads only A-half wm; wave wn reads only B-half wn>>1.
// Per tile t (dbuf t&1), 4 phases x 16 MFMA (quadrant x K=64):
//   P0: read a_lo(8) + b_lo(4); bar; MFMA m0-3 x n0-1; bar
//   P1: read b_hi(4);           bar; MFMA m0-3 x n2-3; bar
//   P2: read a_hi(8); stage B halves of t+2 (B last read in P1 -> safe);
//                               bar; MFMA m4-7 x n0-1; bar
//   P3: stage A halves of t+2 (A last read in P2 -> safe);
//                               bar; MFMA m4-7 x n2-3; vmcnt(8); bar
// vmcnt(8): the 8 newest outstanding loads are tile t+2's; tile t+1's 8
// (issued during t-1) are forced landed before the barrier every wave must
// pass before reading t+1.  Loads never drain in steady state (T4).
// Swizzle: LDS slot q of row r holds global k-octet q^(r&7); read octet o
// at slot o^(r&7) (2-way residual conflict = free).  T1 remap; T5 setprio.
// EPI: 0 = bf16, 1 = bias+relu bf16, 2 = bf16 split-K partial at z*M*N.
template <int EPI>
__global__ __launch_bounds__(512, 2) void k_g64(
    const __hip_bfloat16* __restrict__ A, const __hip_bfloat16* __restrict__ BT,
    void* __restrict__ Cout, const float* __restrict__ bias,
    int M, int N, int K, int lda, int ldb) {
  constexpr int BM = 256, BK = 64;
  __shared__ __align__(16) short As[2][2][128 * 64];  // [dbuf][half] 16KB each
  __shared__ __align__(16) short Bs[2][2][128 * 64];
  int tid = threadIdx.x, lane = tid & 63, wave = tid >> 6;
  int wm = wave >> 2, wn = wave & 3;
  int fr = lane & 15, fg = lane >> 4;
  int bx, by, bz;
  xcd_remap(bx, by, bz);
  int m0 = bx * BM, n0 = by * 256;
  size_t koff = (size_t)bz * K;
  const short* Ab = (const short*)A + koff;
  const short* Bb = (const short*)BT + koff;

  // staging geometry: chunk c = i*512+tid -> row=c>>3 (0..127), slot=c&7,
  // source octet = slot^(row&7)  [inverse of read swizzle]
  int srow0 = tid >> 3, soct0 = (tid & 7) ^ (srow0 & 7);
  int srow1 = 64 + srow0, soct1 = (tid & 7) ^ (srow1 & 7);
  int dst0 = (wave * 64) * 16, dst1 = (512 + wave * 64) * 16;

  auto stA = [&](int db, int hf, int T) {
    GLD16(Ab + (size_t)(m0 + hf * 128 + srow0) * lda + T * BK + soct0 * 8,
          (char*)&As[db][hf][0] + dst0);
    GLD16(Ab + (size_t)(m0 + hf * 128 + srow1) * lda + T * BK + soct1 * 8,
          (char*)&As[db][hf][0] + dst1);
  };
  auto stB = [&](int db, int hf, int T) {
    GLD16(Bb + (size_t)(n0 + hf * 128 + srow0) * ldb + T * BK + soct0 * 8,
          (char*)&Bs[db][hf][0] + dst0);
    GLD16(Bb + (size_t)(n0 + hf * 128 + srow1) * ldb + T * BK + soct1 * 8,
          (char*)&Bs[db][hf][0] + dst1);
  };

  f32x4 acc[8][4];
#pragma unroll
  for (int m = 0; m < 8; m++)
#pragma unroll
    for (int n = 0; n < 4; n++) acc[m][n] = f32x4{0.f, 0.f, 0.f, 0.f};

  const int nt = K / BK;  // 16 for all uses
  stA(0, 0, 0); stA(0, 1, 0); stB(0, 0, 0); stB(0, 1, 0);
  stA(1, 0, 1); stA(1, 1, 1); stB(1, 0, 1); stB(1, 1, 1);
  WAITVM(8);  // tile 0's 8 loads landed; tile 1's in flight
  __builtin_amdgcn_s_barrier();

  int bbase = (wn & 1) * 64;
  for (int t = 0; t < nt; t++) {
    int db = t & 1;
    const char* Ah = (const char*)&As[db][wm][0];
    const char* Bh = (const char*)&Bs[db][wn >> 1][0];
    bf16x8 alo[2][4], ahi[2][4], blo[2][2], bhi[2][2];
    // ---- P0 ----
#pragma unroll
    for (int ks = 0; ks < 2; ks++)
#pragma unroll
      for (int mt = 0; mt < 4; mt++) {
        int row = mt * 16 + fr;
        alo[ks][mt] = *(const bf16x8*)(Ah + row * 128 +
                                       (((ks * 4 + fg) ^ (row & 7)) << 4));
      }
#pragma unroll
    for (int ks = 0; ks < 2; ks++)
#pragma unroll
      for (int n = 0; n < 2; n++) {
        int row = bbase + n * 16 + fr;
        blo[ks][n] = *(const bf16x8*)(Bh + row * 128 +
                                      (((ks * 4 + fg) ^ (row & 7)) << 4));
      }
    __builtin_amdgcn_s_barrier();
    __builtin_amdgcn_s_setprio(1);
#pragma unroll
    for (int ks = 0; ks < 2; ks++)
#pragma unroll
      for (int mt = 0; mt < 4; mt++)
#pragma unroll
        for (int n = 0; n < 2; n++)
          acc[mt][n] = __builtin_amdgcn_mfma_f32_16x16x32_bf16(
              alo[ks][mt], blo[ks][n], acc[mt][n], 0, 0, 0);
    __builtin_amdgcn_s_setprio(0);
    __builtin_amdgcn_s_barrier();
    // ---- P1 ----
#pragma unroll
    for (int ks = 0; ks < 2; ks++)
#pragma unroll
      for (int n = 0; n < 2; n++) {
        int row = bbase + (n + 2) * 16 + fr;
        bhi[ks][n] = *(const bf16x8*)(Bh + row * 128 +
                                      (((ks * 4 + fg) ^ (row & 7)) << 4));
      }
    __builtin_amdgcn_s_barrier();
    __builtin_amdgcn_s_setprio(1);
#pragma unroll
    for (int ks = 0; ks < 2; ks++)
#pragma unroll
      for (int mt = 0; mt < 4; mt++)
#pragma unroll
        for (int n = 0; n < 2; n++)
          acc[mt][n + 2] = __builtin_amdgcn_mfma_f32_16x16x32_bf16(
              alo[ks][mt], bhi[ks][n], acc[mt][n + 2], 0, 0, 0);
    __builtin_amdgcn_s_setprio(0);
    __builtin_amdgcn_s_barrier();
    // ---- P2 ----
#pragma unroll
    for (int ks = 0; ks < 2; ks++)
#pragma unroll
      for (int mt = 0; mt < 4; mt++) {
        int row = (mt + 4) * 16 + fr;
        ahi[ks][mt] = *(const bf16x8*)(Ah + row * 128 +
                                       (((ks * 4 + fg) ^ (row & 7)) << 4));
      }
    if (t + 2 < nt) { stB(db, 0, t + 2); stB(db, 1, t + 2); }
    __builtin_amdgcn_s_barrier();
    __builtin_amdgcn_s_setprio(1);
#pragma unroll
    for (int ks = 0; ks < 2; ks++)
#pragma unroll
      for (int mt = 0; mt < 4; mt++)
#pragma unroll
        for (int n = 0; n < 2; n++)
          acc[mt + 4][n] = __builtin_amdgcn_mfma_f32_16x16x32_bf16(
              ahi[ks][mt], blo[ks][n], acc[mt + 4][n], 0, 0, 0);
    __builtin_amdgcn_s_setprio(0);
    __builtin_amdgcn_s_barrier();
    // ---- P3 ----
    if (t + 2 < nt) { stA(db, 0, t + 2); stA(db, 1, t + 2); }
    __builtin_amdgcn_s_barrier();
    __builtin_amdgcn_s_setprio(1);
#pragma unroll
    for (int ks = 0; ks < 2; ks++)
#pragma unroll
      for (int mt = 0; mt < 4; mt++)
#pragma unroll
        for (int n = 0; n < 2; n++)
          acc[mt + 4][n + 2] = __builtin_amdgcn_mfma_f32_16x16x32_bf16(
              ahi[ks][mt], bhi[ks][n], acc[mt + 4][n + 2], 0, 0, 0);
    __builtin_amdgcn_s_setprio(0);
    if (t + 2 < nt) { WAITVM(8); } else { WAITVM(0); }
    __builtin_amdgcn_s_barrier();
  }

#pragma unroll
  for (int mt = 0; mt < 8; mt++)
#pragma unroll
    for (int n = 0; n < 4; n++) {
      int col = n0 + wn * 64 + n * 16 + fr;
      float bv = (EPI == 1) ? bias[col] : 0.f;
#pragma unroll
      for (int j = 0; j < 4; j++) {
        int row = m0 + wm * 128 + mt * 16 + fg * 4 + j;
        float v = acc[mt][n][j];
        if (EPI == 1) { v += bv; v = fmaxf(v, 0.f); }
        if (EPI == 2)
          ((__hip_bfloat16*)Cout)[(size_t)bz * M * N + (size_t)row * N + col] =
              __float2bfloat16(v);
        else
          ((__hip_bfloat16*)Cout)[(size_t)row * N + col] = __float2bfloat16(v);
      }
    }
}

// ---------------- r8-proven 2-phase GEMM (kept for Wo) --------------------
template <int BN, int EPI>
__global__ __launch_bounds__(512, 2) void k_gemm8(
    const __hip_bfloat16* __restrict__ A, const __hip_bfloat16* __restrict__ BT,
    void* __restrict__ Cout, const float* __restrict__ bias,
    int M, int N, int K, int lda, int ldb) {
  constexpr int BM = 256, BK = 32;
  constexpr int FN = BN / 64;
  __shared__ __align__(16) short As[4][BM * BK];
  __shared__ __align__(16) short Bs[4][BN * BK];
  int tid = threadIdx.x, lane = tid & 63, wave = tid >> 6;
  int wm = wave >> 2, wn = wave & 3;
  int fr = lane & 15, fg = lane >> 4;
  int bx, by, bz;
  xcd_remap(bx, by, bz);
  int m0 = bx * BM, n0 = by * BN;
  size_t koff = (size_t)bz * K;
  const short* Ab = (const short*)A + koff;
  const short* Bb = (const short*)BT + koff;

  int r0 = tid >> 2, s0 = (tid & 3) ^ ((r0 >> 1) & 3);
  int r1 = 128 + r0, s1 = (tid & 3) ^ ((r1 >> 1) & 3);
  const short* pA0 = Ab + (size_t)(m0 + r0) * lda + s0 * 8;
  const short* pA1 = Ab + (size_t)(m0 + r1) * lda + s1 * 8;
  const short* pB0 = Bb + (size_t)(n0 + r0) * ldb + s0 * 8;
  const short* pB1 = (BN == 256) ? Bb + (size_t)(n0 + r1) * ldb + s1 * 8 : pB0;
  int dst0 = (wave * 64) * 16;
  int dst1 = (512 + wave * 64) * 16;

  auto stageA = [&](int d, int T) {
    GLD16(pA0 + T * BK, (char*)&As[d][0] + dst0);
    GLD16(pA1 + T * BK, (char*)&As[d][0] + dst1);
  };
  auto stageB = [&](int d, int T) {
    GLD16(pB0 + T * BK, (char*)&Bs[d][0] + dst0);
    if constexpr (BN == 256) GLD16(pB1 + T * BK, (char*)&Bs[d][0] + dst1);
  };

  f32x4 acc[8][FN];
#pragma unroll
  for (int m = 0; m < 8; m++)
#pragma unroll
    for (int n = 0; n < FN; n++) acc[m][n] = f32x4{0.f, 0.f, 0.f, 0.f};

  const int nt = K / BK;
  stageA(0, 0); stageB(0, 0);
  stageA(1, 1); stageB(1, 1);
  stageA(2, 2); stageB(2, 2);
  if (BN == 256) { WAITVM(8); } else { WAITVM(6); }
  __builtin_amdgcn_s_barrier();

  for (int t = 0; t < nt; t++) {
    int d = t & 3, pf = (t + 3) & 3;
    bool dopf = (t + 3) < nt;
    const char* Al = (const char*)&As[d][0];
    const char* Bl = (const char*)&Bs[d][0];
    bf16x8 a[8], b[2];
#pragma unroll
    for (int mt = 0; mt < 8; mt++) {
      int row = wm * 128 + mt * 16 + fr;
      a[mt] = *(const bf16x8*)(Al + row * 64 + ((fg ^ ((row >> 1) & 3)) << 4));
    }
#pragma unroll
    for (int n = 0; n < 2; n++) {
      int row = wn * 32 + n * 16 + fr;
      b[n] = *(const bf16x8*)(Bl + row * 64 + ((fg ^ ((row >> 1) & 3)) << 4));
    }
    if (dopf) { stageA(pf, t + 3); stageB(pf, t + 3); }
    if (t < nt - 3) { WAITVM(6); }
    else if (t == nt - 3) { WAITVM(3); }
    else if (t == nt - 2) { WAITVM(0); }
    __builtin_amdgcn_s_barrier();
    __builtin_amdgcn_s_setprio(1);
#pragma unroll
    for (int mt = 0; mt < 8; mt++)
#pragma unroll
      for (int n = 0; n < 2; n++)
        acc[mt][n] = __builtin_amdgcn_mfma_f32_16x16x32_bf16(a[mt], b[n],
                                                             acc[mt][n], 0, 0, 0);
    __builtin_amdgcn_s_setprio(0);
    __builtin_amdgcn_s_barrier();
  }

#pragma unroll
  for (int mt = 0; mt < 8; mt++)
#pragma unroll
    for (int n = 0; n < FN; n++) {
      int col = n0 + wn * (BN / 4) + n * 16 + fr;
      float bv = (EPI == 1) ? bias[col] : 0.f;
#pragma unroll
      for (int j = 0; j < 4; j++) {
        int row = m0 + wm * 128 + mt * 16 + fg * 4 + j;
        float v = acc[mt][n][j];
        if (EPI == 1) { v += bv; v = fmaxf(v, 0.f); }
        if (EPI == 2)
          ((__hip_bfloat16*)Cout)[(size_t)bz * M * N + (size_t)row * N + col] =
              __float2bfloat16(v);
        else
          ((__hip_bfloat16*)Cout)[(size_t)row * N + col] = __float2bfloat16(v);
      }
    }
}

// ---------------- V transpose: qkv v-slice -> vT[bh][64 d][2048 t] --------
__global__ __launch_bounds__(256) void k_vtrans(
    const __hip_bfloat16* __restrict__ qkv, __hip_bfloat16* __restrict__ vT) {
  __shared__ short tile[64][68];
  int bh = blockIdx.x;
  int tb = blockIdx.y;
  int b = bh >> 4, h = bh & 15;
  int tid = threadIdx.x;
#pragma unroll
  for (int i = 0; i < 2; i++) {
    int c = i * 256 + tid;
    int trow = c >> 3, seg = c & 7;
    bf16x8 v = *(const bf16x8*)((const short*)qkv +
        (size_t)(b * TS + tb * 64 + trow) * 3072 + 2048 + h * TDH + seg * 8);
    s16x4 lo = {v[0], v[1], v[2], v[3]}, hi = {v[4], v[5], v[6], v[7]};
    *(s16x4*)&tile[trow][seg * 8] = lo;
    *(s16x4*)&tile[trow][seg * 8 + 4] = hi;
  }
  __syncthreads();
#pragma unroll
  for (int i2 = 0; i2 < 2; i2++) {
    int c = i2 * 256 + tid;
    int d = c >> 3, ts = c & 7;
    bf16x8 o;
#pragma unroll
    for (int j = 0; j < 8; j++) o[j] = tile[ts * 8 + j][d];
    *(bf16x8*)((short*)vT + (size_t)bh * TDH * TS + (size_t)d * TS +
               tb * 64 + ts * 8) = o;
  }
}

// ---------------- sliding-window attention (MFMA) --------------------------
__global__ __launch_bounds__(256) void k_attn(
    const __hip_bfloat16* __restrict__ qkv, const __hip_bfloat16* __restrict__ vT,
    const float* __restrict__ rpe, __hip_bfloat16* __restrict__ out) {
  __shared__ __align__(16) short K_lds[128 * 64];
  __shared__ __align__(16) short VT_lds[64 * 128];
  __shared__ __align__(16) short P_lds[4][16 * 136];
  __shared__ float rpe_lds[TC];
  int tid = threadIdx.x, lane = tid & 63, wave = tid >> 6;
  int fr = lane & 15, g = lane >> 4;
  int blk = blockIdx.x;
  int qt = blk & 31, bh = blk >> 5;
  int h = bh & 15, b = bh >> 4;
  int t0 = qt * 64;
  const short* qg = (const short*)qkv;

  if (tid < TC) rpe_lds[tid] = rpe[h * TC + tid];

#pragma unroll
  for (int i = 0; i < 4; i++) {
    int cb = i * 256 + wave * 64;
    int c = cb + lane;
    int row = c >> 3, slot = c & 7;
    int seg = slot ^ (row & 7);
    int kr = t0 - 64 + row; if (kr < 0) kr = 0;
    GLD16(qg + ((size_t)(b * TS + kr) * 3072 + 1024 + h * TDH + seg * 8),
          (char*)K_lds + cb * 16);
  }
  const short* vg = (const short*)vT + (size_t)bh * TDH * TS;
#pragma unroll
  for (int i = 0; i < 4; i++) {
    int cb = i * 256 + wave * 64;
    int c = cb + lane;
    int row = c >> 4, slot = c & 15;
    int seg = slot ^ (row & 15);
    int tc = t0 - 64 + seg * 8; if (tc < 0) tc = 0;
    GLD16(vg + (size_t)row * TS + tc, (char*)VT_lds + cb * 16);
  }

  int qrow = t0 + wave * 16 + fr;
  const short* qptr = qg + ((size_t)(b * TS + qrow) * 3072 + h * TDH + g * 8);
  bf16x8 qf0 = *(const bf16x8*)qptr;
  bf16x8 qf1 = *(const bf16x8*)(qptr + 32);

  __syncthreads();

  f32x4 S[8] = {};
#pragma unroll
  for (int kk = 0; kk < 2; kk++) {
    bf16x8 a = kk ? qf1 : qf0;
#pragma unroll
    for (int nt = 0; nt < 8; nt++) {
      int row = nt * 16 + fr;
      int slot = (kk * 4 + g) ^ (row & 7);
      bf16x8 bfrag = *(const bf16x8*)((const char*)K_lds + row * 128 + slot * 16);
      S[nt] = __builtin_amdgcn_mfma_f32_16x16x32_bf16(a, bfrag, S[nt], 0, 0, 0);
    }
  }

  int wq = wave * 16;
#pragma unroll
  for (int r = 0; r < 4; r++) {
    int ql = g * 4 + r;
    float sc[8];
    float m = -3.4028235e38f;
#pragma unroll
    for (int nt = 0; nt < 8; nt++) {
      int jj = nt * 16 + fr;
      int d = wq + ql + 64 - jj;
      bool valid = (d >= 0) && (d < TC) && (t0 - 64 + jj >= 0);
      float v = valid ? (S[nt][r] * 0.125f + rpe_lds[d & (TC - 1)])
                      : -3.4028235e38f;
      sc[nt] = v;
      m = fmaxf(m, v);
    }
#pragma unroll
    for (int o = 1; o < 16; o <<= 1) m = fmaxf(m, __shfl_xor(m, o));
    float p[8], sum = 0.f;
#pragma unroll
    for (int nt = 0; nt < 8; nt++) { p[nt] = __expf(sc[nt] - m); sum += p[nt]; }
#pragma unroll
    for (int o = 1; o < 16; o <<= 1) sum += __shfl_xor(sum, o);
    float rs = 1.0f / sum;
#pragma unroll
    for (int nt = 0; nt < 8; nt++)
      P_lds[wave][ql * 136 + nt * 16 + fr] = f2bf(p[nt] * rs);
  }

  f32x4 O[4] = {};
#pragma unroll
  for (int kk = 0; kk < 4; kk++) {
    bf16x8 pa = *(const bf16x8*)((const char*)&P_lds[wave][0] +
                                 fr * 272 + kk * 64 + g * 16);
#pragma unroll
    for (int dt = 0; dt < 4; dt++) {
      int row = dt * 16 + fr;
      int slot = (kk * 4 + g) ^ (row & 15);
      bf16x8 vb = *(const bf16x8*)((const char*)VT_lds + row * 256 + slot * 16);
      O[dt] = __builtin_amdgcn_mfma_f32_16x16x32_bf16(pa, vb, O[dt], 0, 0, 0);
    }
  }

  size_t ob = ((size_t)(b * TS + t0 + wq + g * 4)) * TD + h * TDH;
#pragma unroll
  for (int dt = 0; dt < 4; dt++)
#pragma unroll
    for (int r = 0; r < 4; r++)
      ((short*)out)[ob + (size_t)r * TD + dt * 16 + fr] = f2bf(O[dt][r]);
}

// ---------------- LayerNorm (two-pass, fused residual + split-K sum) ------
DEVI float block_sum(float v, float* red) {
  for (int o = 32; o; o >>= 1) v += __shfl_xor(v, o);
  int wave = threadIdx.x >> 6;
  if ((threadIdx.x & 63) == 0) red[wave] = v;
  __syncthreads();
  float r = red[0] + red[1] + red[2] + red[3];
  __syncthreads();
  return r;
}

__global__ __launch_bounds__(256) void k_ln1(
    const __hip_bfloat16* __restrict__ hB, const __hip_bfloat16* __restrict__ P0,
    const __hip_bfloat16* __restrict__ P1, const float* __restrict__ scale,
    const float* __restrict__ offset, float* __restrict__ outf,
    __hip_bfloat16* __restrict__ outb) {
  __shared__ float red[4];
  int row = blockIdx.x, tid = threadIdx.x;
  size_t base = (size_t)row * TD + tid * 4;
  s16x4 hv = *(const s16x4*)((const short*)hB + base);
  s16x4 a0 = *(const s16x4*)((const short*)P0 + base);
  s16x4 a1 = *(const s16x4*)((const short*)P1 + base);
  f32x4 xv;
  for (int j = 0; j < 4; j++) xv[j] = bf2f(hv[j]) + bf2f(a0[j]) + bf2f(a1[j]);
  float s = xv[0] + xv[1] + xv[2] + xv[3];
  s = block_sum(s, red);
  float mu = s * (1.f / TD);
  float s2 = 0.f;
  for (int j = 0; j < 4; j++) { float dlt = xv[j] - mu; s2 += dlt * dlt; }
  s2 = block_sum(s2, red);
  float rs = rsqrtf(s2 * (1.f / TD) + 1e-5f);
  f32x4 sc = *(const f32x4*)(scale + tid * 4);
  f32x4 of = *(const f32x4*)(offset + tid * 4);
  f32x4 y;
  for (int j = 0; j < 4; j++) y[j] = (xv[j] - mu) * rs * sc[j] + of[j];
  *(f32x4*)(outf + base) = y;
  s16x4 pb;
  for (int j = 0; j < 4; j++) pb[j] = f2bf(y[j]);
  *(s16x4*)((short*)outb + base) = pb;
}

// ln2: in = P0+P1+P2+P3 (bf16 partials) + R (f32) + bias; out f32 (d_out)
__global__ __launch_bounds__(256) void k_ln2(
    const __hip_bfloat16* __restrict__ P0, const __hip_bfloat16* __restrict__ P1,
    const __hip_bfloat16* __restrict__ P2, const __hip_bfloat16* __restrict__ P3,
    const float* __restrict__ R, const float* __restrict__ bias,
    const float* __restrict__ scale, const float* __restrict__ offset,
    float* __restrict__ outf) {
  __shared__ float red[4];
  int row = blockIdx.x, tid = threadIdx.x;
  size_t base = (size_t)row * TD + tid * 4;
  s16x4 a0 = *(const s16x4*)((const short*)P0 + base);
  s16x4 a1 = *(const s16x4*)((const short*)P1 + base);
  s16x4 a2 = *(const s16x4*)((const short*)P2 + base);
  s16x4 a3 = *(const s16x4*)((const short*)P3 + base);
  f32x4 rv = *(const f32x4*)(R + base);
  f32x4 bi = *(const f32x4*)(bias + tid * 4);
  f32x4 xv;
  for (int j = 0; j < 4; j++)
    xv[j] = bf2f(a0[j]) + bf2f(a1[j]) + bf2f(a2[j]) + bf2f(a3[j]) + rv[j] + bi[j];
  float s = xv[0] + xv[1] + xv[2] + xv[3];
  s = block_sum(s, red);
  float mu = s * (1.f / TD);
  float s2 = 0.f;
  for (int j = 0; j < 4; j++) { float dlt = xv[j] - mu; s2 += dlt * dlt; }
  s2 = block_sum(s2, red);
  float rs = rsqrtf(s2 * (1.f / TD) + 1e-5f);
  f32x4 sc = *(const f32x4*)(scale + tid * 4);
  f32x4 of = *(const f32x4*)(offset + tid * 4);
  f32x4 y;
  for (int j = 0; j < 4; j++) y[j] = (xv[j] - mu) * rs * sc[j] + of[j];
  *(f32x4*)(outf + base) = y;
}

// --------------------------------------------------------------------------
extern "C" void kernel_launch(void* const* d_in, const int* in_sizes, int n_in,
                              void* d_out, int out_size, void* d_ws, size_t ws_size,
                              hipStream_t stream) {
  const float* x    = (const float*)d_in[0];
  const float* pos  = (const float*)d_in[2];
  const float* rpe  = (const float*)d_in[3];
  const float* Wq   = (const float*)d_in[4];
  const float* Wk   = (const float*)d_in[5];
  const float* Wv   = (const float*)d_in[6];
  const float* Wo   = (const float*)d_in[7];
  const float* ln1s = (const float*)d_in[8];
  const float* ln1o = (const float*)d_in[9];
  const float* W1   = (const float*)d_in[10];
  const float* b1   = (const float*)d_in[11];
  const float* W2   = (const float*)d_in[12];
  const float* b2   = (const float*)d_in[13];
  const float* ln2s = (const float*)d_in[14];
  const float* ln2o = (const float*)d_in[15];

  char* ws = (char*)d_ws;
  const size_t MB = 1ull << 20;
  __hip_bfloat16* WqkvT = (__hip_bfloat16*)(ws + 0 * MB);   // 6 MB
  __hip_bfloat16* WoT   = (__hip_bfloat16*)(ws + 6 * MB);   // 2 MB
  __hip_bfloat16* W1T   = (__hip_bfloat16*)(ws + 8 * MB);   // 8 MB
  __hip_bfloat16* W2T   = (__hip_bfloat16*)(ws + 16 * MB);  // 8 MB
  __hip_bfloat16* hB    = (__hip_bfloat16*)(ws + 24 * MB);  // 8 MB (h until ln1)
  __hip_bfloat16* qkv   = (__hip_bfloat16*)(ws + 32 * MB);  // 24 MB
  __hip_bfloat16* aoB   = (__hip_bfloat16*)(ws + 56 * MB);  // 8 MB
  __hip_bfloat16* oB2   = (__hip_bfloat16*)(ws + 64 * MB);  // 16 MB, 2 bf16 partials
  float*          atF   = (float*)(ws + 96 * MB);           // 16 MB
  __hip_bfloat16* atB   = (__hip_bfloat16*)(ws + 24 * MB);  // 8 MB (aliases hB; RMW-safe)
  __hip_bfloat16* ff1   = (__hip_bfloat16*)(ws + 32 * MB);  // 32 MB (aliases qkv+aoB)
  __hip_bfloat16* ff2   = (__hip_bfloat16*)(ws + 64 * MB);  // 32 MB, 4 bf16 partials
  __hip_bfloat16* vTb   = (__hip_bfloat16*)(ws + 112 * MB); // 8 MB
  // high-water: 120 MB

  dim3 blk(256), blk5(512);

  k_trans_all<<<16384, blk, 0, stream>>>(Wq, Wk, Wv, Wo, W1, W2,
                                         WqkvT, WoT, W1T, W2T, x, pos, hB);

  // QKV fused: (4096 x 1024) * (3072 x 1024)^T -> bf16 qkv
  k_g64<0><<<dim3(TM / 256, 3072 / 256, 1), blk5, 0, stream>>>(
      hB, WqkvT, qkv, nullptr, TM, 3072, TD, TD, TD);

  k_vtrans<<<dim3(TB * TH, TS / 64), blk, 0, stream>>>(qkv, vTb);
  k_attn<<<TB * TH * (TS / 64), blk, 0, stream>>>(qkv, vTb, rpe, aoB);

  // Wo: BN=128, split-K=2 -> two bf16 partials (r8-proven path)
  k_gemm8<128, 2><<<dim3(TM / 256, TD / 128, 2), blk5, 0, stream>>>(
      aoB, WoT, oB2, nullptr, TM, TD, TD / 2, TD, TD);

  k_ln1<<<TM, blk, 0, stream>>>(hB, oB2, oB2 + (size_t)TM * TD, ln1s, ln1o,
                                atF, atB);

  // FFN1: bias+relu -> bf16 (grid 16x16 = 256 blocks)
  k_g64<1><<<dim3(TM / 256, TFF / 256, 1), blk5, 0, stream>>>(
      atB, W1T, ff1, b1, TM, TFF, TD, TD, TD);

  // FFN2: BN=256, split-K=4 -> four bf16 partials (grid 16x4x4 = 256 blocks)
  k_g64<2><<<dim3(TM / 256, TD / 256, 4), blk5, 0, stream>>>(
      ff1, W2T, ff2, nullptr, TM, TD, TFF / 4, TFF, TFF);

  k_ln2<<<TM, blk, 0, stream>>>(ff2, ff2 + (size_t)TM * TD,
                                ff2 + (size_t)2 * TM * TD, ff2 + (size_t)3 * TM * TD,
                                atF, b2, ln2s, ln2o, (float*)d_out);
}

// Round 12
// 183.736 us; speedup vs baseline: 1.2992x; 1.0328x over previous
//
#include <hip/hip_runtime.h>
#include <hip/hip_bf16.h>

#define DEVI static __device__ __forceinline__

typedef __attribute__((ext_vector_type(4))) float f32x4;
typedef __attribute__((ext_vector_type(8))) short bf16x8;
typedef __attribute__((ext_vector_type(4))) short s16x4;

constexpr int TB  = 2;      // batch
constexpr int TS  = 2048;   // seq len
constexpr int TD  = 1024;   // model dim
constexpr int TH  = 16;     // heads
constexpr int TDH = 64;     // head dim
constexpr int TC  = 64;     // window size
constexpr int TFF = 4096;   // ffn dim
constexpr int TM  = TB * TS;  // 4096 rows

DEVI float bf2f(short s) {
  return __builtin_bit_cast(float, (unsigned)((unsigned short)s) << 16);
}
DEVI short f2bf(float f) {
  return __builtin_bit_cast(short, __float2bfloat16(f));
}

// async global->LDS, 16B per lane, dest = wave-uniform base + lane*16
#define GLD16(gp, lp)                                              \
  __builtin_amdgcn_global_load_lds(                                \
      (const __attribute__((address_space(1))) void*)(gp),         \
      (__attribute__((address_space(3))) void*)(lp), 16, 0, 0)

// counted vmcnt wait (N must be a LITERAL; dispatch constexpr values below)
#define WAITVM(N) asm volatile("s_waitcnt vmcnt(" #N ")" ::: "memory")

// T1 XCD-aware bijective remap (requires nb%8==0, gx%8==0; all our grids)
DEVI void xcd_remap(int& bx, int& by, int& bz) {
  int gx = gridDim.x, gy = gridDim.y;
  int nb = gx * gy * gridDim.z;
  int phys = blockIdx.x + gx * (blockIdx.y + gy * blockIdx.z);
  int chunk = nb >> 3;
  int logical = (phys & 7) * chunk + (phys >> 3);
  int perz = gx * gy;
  bz = logical / perz;
  int l2 = logical - bz * perz;
  int g = l2 / (8 * gy);
  int r = l2 - g * 8 * gy;
  by = r >> 3;
  bx = g * 8 + (r & 7);
}

// ---------------- weight transposes + addpos in ONE dispatch --------------
__global__ __launch_bounds__(256) void k_trans_all(
    const float* __restrict__ Wq, const float* __restrict__ Wk,
    const float* __restrict__ Wv, const float* __restrict__ Wo,
    const float* __restrict__ W1, const float* __restrict__ W2,
    __hip_bfloat16* __restrict__ WqkvT, __hip_bfloat16* __restrict__ WoT,
    __hip_bfloat16* __restrict__ W1T, __hip_bfloat16* __restrict__ W2T,
    const float* __restrict__ x, const float* __restrict__ pos,
    __hip_bfloat16* __restrict__ hb) {
  int bid = blockIdx.x;
  if (bid >= 12288) {                    // addpos: h = x + pos[t % C]
    int i = (bid - 12288) * 256 + threadIdx.x;
    int e = i * 4;
    int d = e & (TD - 1);
    int t = (e / TD) & (TS - 1);
    f32x4 xv = *(const f32x4*)(x + e);
    f32x4 pv = *(const f32x4*)(pos + (size_t)(t & (TC - 1)) * TD + d);
    s16x4 hb4;
    for (int j = 0; j < 4; j++) hb4[j] = f2bf(xv[j] + pv[j]);
    *(s16x4*)((short*)hb + e) = hb4;
    return;
  }
  __shared__ float tile[32][33];
  const float* src; __hip_bfloat16* dst;
  int K, N, n0, k0;
  if (bid < 4096) {                      // Wq,Wk,Wv,Wo : 1024x1024 each
    int m = bid >> 10, t = bid & 1023;
    src = (m == 0) ? Wq : (m == 1) ? Wk : (m == 2) ? Wv : Wo;
    dst = (m == 3) ? WoT : WqkvT + (size_t)m * TD * TD;
    K = TD; N = TD; n0 = (t & 31) * 32; k0 = (t >> 5) * 32;
  } else if (bid < 8192) {               // W1 : 1024x4096
    int t = bid - 4096;
    src = W1; dst = W1T; K = TD; N = TFF;
    n0 = (t & 127) * 32; k0 = (t >> 7) * 32;
  } else {                               // W2 : 4096x1024
    int t = bid - 8192;
    src = W2; dst = W2T; K = TFF; N = TD;
    n0 = (t & 31) * 32; k0 = (t >> 5) * 32;
  }
  int tx = threadIdx.x & 31, ty = threadIdx.x >> 5;  // 32 x 8
  for (int i = 0; i < 32; i += 8)
    tile[ty + i][tx] = src[(size_t)(k0 + ty + i) * N + n0 + tx];
  __syncthreads();
  for (int i = 0; i < 32; i += 8)
    dst[(size_t)(n0 + ty + i) * K + k0 + tx] = __float2bfloat16(tile[tx][ty + i]);
}

// ---------------- m201-template GEMM: BK=64, 4 quadrant phases, BN=256|192 -
// C = A(MxK)*BT(NxK)^T.  BM=256, BK=64, 512 thr = 8 waves (2M x 4N),
// per-wave C = 128 x BN/4.  LDS: 2 dbuf x [BM][64] A + [BN][64] B
// (128 KiB | 112 KiB).  Per tile t (dbuf t&1), 4 phases:
//   P0: read a_lo(8) + b n0-1(4); bar; MFMA m-lo x n0-1 (16); bar
//   P1: read b n2..(2*NHI);       bar; MFMA m-lo x n-hi (8*NHI); bar
//   P2: read a_hi(8); stage B(t+2) (B of t last read in P1 -> safe);
//                                 bar; MFMA m-hi x n0-1 (16); bar
//   P3: stage A(t+2) (A of t last read in P2 -> safe);
//                                 bar; MFMA m-hi x n-hi; vmcnt(LPT); bar
// vmcnt(LPT): LPT newest outstanding loads are t+2's; t+1's LPT are forced
// landed before the barrier every wave passes before reading t+1.  Loads
// never drain in steady state (T4).  Swizzle: LDS slot q of row r holds
// k-octet q^(r&7) (2-way residual = free).  T1 remap; T5 setprio.
// EPI: 0 = bf16, 1 = bias+relu bf16, 2 = bf16 split-K partial at z*M*N.
template <int BN, int EPI>
__global__ __launch_bounds__(512, 2) void k_g64(
    const __hip_bfloat16* __restrict__ A, const __hip_bfloat16* __restrict__ BT,
    void* __restrict__ Cout, const float* __restrict__ bias,
    int M, int N, int K, int lda, int ldb) {
  constexpr int BM = 256, BK = 64;
  constexpr int FN  = BN / 64;        // n-frags per wave: 4 or 3
  constexpr int NHI = FN - 2;         // 2 or 1
  constexpr int NB  = BN / 64;        // B stage calls: 4 or 3
  __shared__ __align__(16) short As[2][BM * BK];  // 32 KB each
  __shared__ __align__(16) short Bs[2][BN * BK];  // 32 | 24 KB each
  int tid = threadIdx.x, lane = tid & 63, wave = tid >> 6;
  int wm = wave >> 2, wn = wave & 3;
  int fr = lane & 15, fg = lane >> 4;
  int bx, by, bz;
  xcd_remap(bx, by, bz);
  int m0 = bx * BM, n0 = by * BN;
  size_t koff = (size_t)bz * K;
  const short* Ab = (const short*)A + koff;
  const short* Bb = (const short*)BT + koff;

  // staging: chunk c = i*512+tid -> row = i*64 + (tid>>3), slot = tid&7,
  // source octet = slot ^ (row&7); (i*64)&7==0 so octet is i-invariant.
  int srow = tid >> 3, soct = (tid & 7) ^ (srow & 7);
  int dstc = (wave * 64) * 16;

  auto stA = [&](int db, int T) {
#pragma unroll
    for (int i = 0; i < 4; i++)
      GLD16(Ab + (size_t)(m0 + i * 64 + srow) * lda + T * BK + soct * 8,
            (char*)&As[db][0] + i * 8192 + dstc);
  };
  auto stB = [&](int db, int T) {
#pragma unroll
    for (int i = 0; i < NB; i++)
      GLD16(Bb + (size_t)(n0 + i * 64 + srow) * ldb + T * BK + soct * 8,
            (char*)&Bs[db][0] + i * 8192 + dstc);
  };
  // vmcnt(loads-per-tile) with literal immediates (asm needs literals)
  auto waitLPT = [&]() {
    if constexpr (BN == 256) { WAITVM(8); } else { WAITVM(7); }
  };

  f32x4 acc[8][FN];
#pragma unroll
  for (int m = 0; m < 8; m++)
#pragma unroll
    for (int n = 0; n < FN; n++) acc[m][n] = f32x4{0.f, 0.f, 0.f, 0.f};

  const int nt = K / BK;  // 16 for all uses
  stA(0, 0); stB(0, 0);
  stA(1, 1); stB(1, 1);
  waitLPT();  // tile 0's loads landed; tile 1's in flight
  __builtin_amdgcn_s_barrier();

  for (int t = 0; t < nt; t++) {
    int db = t & 1;
    const char* Ah = (const char*)&As[db][0] + wm * 128 * 128;  // wm half
    const char* Bl = (const char*)&Bs[db][0];
    bf16x8 alo[2][4], ahi[2][4], blo[2][2], bhi[2][NHI];
    // ---- P0 ----
#pragma unroll
    for (int ks = 0; ks < 2; ks++)
#pragma unroll
      for (int mt = 0; mt < 4; mt++) {
        int rl = mt * 16 + fr;
        alo[ks][mt] = *(const bf16x8*)(Ah + rl * 128 +
                                       (((ks * 4 + fg) ^ (rl & 7)) << 4));
      }
#pragma unroll
    for (int ks = 0; ks < 2; ks++)
#pragma unroll
      for (int n = 0; n < 2; n++) {
        int row = wn * (BN / 4) + n * 16 + fr;
        blo[ks][n] = *(const bf16x8*)(Bl + row * 128 +
                                      (((ks * 4 + fg) ^ (row & 7)) << 4));
      }
    __builtin_amdgcn_s_barrier();
    __builtin_amdgcn_s_setprio(1);
#pragma unroll
    for (int ks = 0; ks < 2; ks++)
#pragma unroll
      for (int mt = 0; mt < 4; mt++)
#pragma unroll
        for (int n = 0; n < 2; n++)
          acc[mt][n] = __builtin_amdgcn_mfma_f32_16x16x32_bf16(
              alo[ks][mt], blo[ks][n], acc[mt][n], 0, 0, 0);
    __builtin_amdgcn_s_setprio(0);
    __builtin_amdgcn_s_barrier();
    // ---- P1 ----
#pragma unroll
    for (int ks = 0; ks < 2; ks++)
#pragma unroll
      for (int n = 0; n < NHI; n++) {
        int row = wn * (BN / 4) + (n + 2) * 16 + fr;
        bhi[ks][n] = *(const bf16x8*)(Bl + row * 128 +
                                      (((ks * 4 + fg) ^ (row & 7)) << 4));
      }
    __builtin_amdgcn_s_barrier();
    __builtin_amdgcn_s_setprio(1);
#pragma unroll
    for (int ks = 0; ks < 2; ks++)
#pragma unroll
      for (int mt = 0; mt < 4; mt++)
#pragma unroll
        for (int n = 0; n < NHI; n++)
          acc[mt][n + 2] = __builtin_amdgcn_mfma_f32_16x16x32_bf16(
              alo[ks][mt], bhi[ks][n], acc[mt][n + 2], 0, 0, 0);
    __builtin_amdgcn_s_setprio(0);
    __builtin_amdgcn_s_barrier();
    // ---- P2 ----
#pragma unroll
    for (int ks = 0; ks < 2; ks++)
#pragma unroll
      for (int mt = 0; mt < 4; mt++) {
        int rl = (mt + 4) * 16 + fr;
        ahi[ks][mt] = *(const bf16x8*)(Ah + rl * 128 +
                                       (((ks * 4 + fg) ^ (rl & 7)) << 4));
      }
    if (t + 2 < nt) stB(db, t + 2);
    __builtin_amdgcn_s_barrier();
    __builtin_amdgcn_s_setprio(1);
#pragma unroll
    for (int ks = 0; ks < 2; ks++)
#pragma unroll
      for (int mt = 0; mt < 4; mt++)
#pragma unroll
        for (int n = 0; n < 2; n++)
          acc[mt + 4][n] = __builtin_amdgcn_mfma_f32_16x16x32_bf16(
              ahi[ks][mt], blo[ks][n], acc[mt + 4][n], 0, 0, 0);
    __builtin_amdgcn_s_setprio(0);
    __builtin_amdgcn_s_barrier();
    // ---- P3 ----
    if (t + 2 < nt) stA(db, t + 2);
    __builtin_amdgcn_s_barrier();
    __builtin_amdgcn_s_setprio(1);
#pragma unroll
    for (int ks = 0; ks < 2; ks++)
#pragma unroll
      for (int mt = 0; mt < 4; mt++)
#pragma unroll
        for (int n = 0; n < NHI; n++)
          acc[mt + 4][n + 2] = __builtin_amdgcn_mfma_f32_16x16x32_bf16(
              ahi[ks][mt], bhi[ks][n], acc[mt + 4][n + 2], 0, 0, 0);
    __builtin_amdgcn_s_setprio(0);
    if (t + 2 < nt) { waitLPT(); } else { WAITVM(0); }
    __builtin_amdgcn_s_barrier();
  }

#pragma unroll
  for (int mt = 0; mt < 8; mt++)
#pragma unroll
    for (int n = 0; n < FN; n++) {
      int col = n0 + wn * (BN / 4) + n * 16 + fr;
      float bv = (EPI == 1) ? bias[col] : 0.f;
#pragma unroll
      for (int j = 0; j < 4; j++) {
        int row = m0 + wm * 128 + mt * 16 + fg * 4 + j;
        float v = acc[mt][n][j];
        if (EPI == 1) { v += bv; v = fmaxf(v, 0.f); }
        if (EPI == 2)
          ((__hip_bfloat16*)Cout)[(size_t)bz * M * N + (size_t)row * N + col] =
              __float2bfloat16(v);
        else
          ((__hip_bfloat16*)Cout)[(size_t)row * N + col] = __float2bfloat16(v);
      }
    }
}

// ---------------- r8-proven 2-phase GEMM (kept for Wo) --------------------
template <int BN, int EPI>
__global__ __launch_bounds__(512, 2) void k_gemm8(
    const __hip_bfloat16* __restrict__ A, const __hip_bfloat16* __restrict__ BT,
    void* __restrict__ Cout, const float* __restrict__ bias,
    int M, int N, int K, int lda, int ldb) {
  constexpr int BM = 256, BK = 32;
  constexpr int FN = BN / 64;
  __shared__ __align__(16) short As[4][BM * BK];
  __shared__ __align__(16) short Bs[4][BN * BK];
  int tid = threadIdx.x, lane = tid & 63, wave = tid >> 6;
  int wm = wave >> 2, wn = wave & 3;
  int fr = lane & 15, fg = lane >> 4;
  int bx, by, bz;
  xcd_remap(bx, by, bz);
  int m0 = bx * BM, n0 = by * BN;
  size_t koff = (size_t)bz * K;
  const short* Ab = (const short*)A + koff;
  const short* Bb = (const short*)BT + koff;

  int r0 = tid >> 2, s0 = (tid & 3) ^ ((r0 >> 1) & 3);
  int r1 = 128 + r0, s1 = (tid & 3) ^ ((r1 >> 1) & 3);
  const short* pA0 = Ab + (size_t)(m0 + r0) * lda + s0 * 8;
  const short* pA1 = Ab + (size_t)(m0 + r1) * lda + s1 * 8;
  const short* pB0 = Bb + (size_t)(n0 + r0) * ldb + s0 * 8;
  const short* pB1 = (BN == 256) ? Bb + (size_t)(n0 + r1) * ldb + s1 * 8 : pB0;
  int dst0 = (wave * 64) * 16;
  int dst1 = (512 + wave * 64) * 16;

  auto stageA = [&](int d, int T) {
    GLD16(pA0 + T * BK, (char*)&As[d][0] + dst0);
    GLD16(pA1 + T * BK, (char*)&As[d][0] + dst1);
  };
  auto stageB = [&](int d, int T) {
    GLD16(pB0 + T * BK, (char*)&Bs[d][0] + dst0);
    if constexpr (BN == 256) GLD16(pB1 + T * BK, (char*)&Bs[d][0] + dst1);
  };

  f32x4 acc[8][FN];
#pragma unroll
  for (int m = 0; m < 8; m++)
#pragma unroll
    for (int n = 0; n < FN; n++) acc[m][n] = f32x4{0.f, 0.f, 0.f, 0.f};

  const int nt = K / BK;
  stageA(0, 0); stageB(0, 0);
  stageA(1, 1); stageB(1, 1);
  stageA(2, 2); stageB(2, 2);
  if (BN == 256) { WAITVM(8); } else { WAITVM(6); }
  __builtin_amdgcn_s_barrier();

  for (int t = 0; t < nt; t++) {
    int d = t & 3, pf = (t + 3) & 3;
    bool dopf = (t + 3) < nt;
    const char* Al = (const char*)&As[d][0];
    const char* Bl = (const char*)&Bs[d][0];
    bf16x8 a[8], b[2];
#pragma unroll
    for (int mt = 0; mt < 8; mt++) {
      int row = wm * 128 + mt * 16 + fr;
      a[mt] = *(const bf16x8*)(Al + row * 64 + ((fg ^ ((row >> 1) & 3)) << 4));
    }
#pragma unroll
    for (int n = 0; n < 2; n++) {
      int row = wn * 32 + n * 16 + fr;
      b[n] = *(const bf16x8*)(Bl + row * 64 + ((fg ^ ((row >> 1) & 3)) << 4));
    }
    if (dopf) { stageA(pf, t + 3); stageB(pf, t + 3); }
    if (t < nt - 3) { WAITVM(6); }
    else if (t == nt - 3) { WAITVM(3); }
    else if (t == nt - 2) { WAITVM(0); }
    __builtin_amdgcn_s_barrier();
    __builtin_amdgcn_s_setprio(1);
#pragma unroll
    for (int mt = 0; mt < 8; mt++)
#pragma unroll
      for (int n = 0; n < 2; n++)
        acc[mt][n] = __builtin_amdgcn_mfma_f32_16x16x32_bf16(a[mt], b[n],
                                                             acc[mt][n], 0, 0, 0);
    __builtin_amdgcn_s_setprio(0);
    __builtin_amdgcn_s_barrier();
  }

#pragma unroll
  for (int mt = 0; mt < 8; mt++)
#pragma unroll
    for (int n = 0; n < FN; n++) {
      int col = n0 + wn * (BN / 4) + n * 16 + fr;
      float bv = (EPI == 1) ? bias[col] : 0.f;
#pragma unroll
      for (int j = 0; j < 4; j++) {
        int row = m0 + wm * 128 + mt * 16 + fg * 4 + j;
        float v = acc[mt][n][j];
        if (EPI == 1) { v += bv; v = fmaxf(v, 0.f); }
        if (EPI == 2)
          ((__hip_bfloat16*)Cout)[(size_t)bz * M * N + (size_t)row * N + col] =
              __float2bfloat16(v);
        else
          ((__hip_bfloat16*)Cout)[(size_t)row * N + col] = __float2bfloat16(v);
      }
    }
}

// ---------------- V transpose: qkv v-slice -> vT[bh][64 d][2048 t] --------
__global__ __launch_bounds__(256) void k_vtrans(
    const __hip_bfloat16* __restrict__ qkv, __hip_bfloat16* __restrict__ vT) {
  __shared__ short tile[64][68];
  int bh = blockIdx.x;
  int tb = blockIdx.y;
  int b = bh >> 4, h = bh & 15;
  int tid = threadIdx.x;
#pragma unroll
  for (int i = 0; i < 2; i++) {
    int c = i * 256 + tid;
    int trow = c >> 3, seg = c & 7;
    bf16x8 v = *(const bf16x8*)((const short*)qkv +
        (size_t)(b * TS + tb * 64 + trow) * 3072 + 2048 + h * TDH + seg * 8);
    s16x4 lo = {v[0], v[1], v[2], v[3]}, hi = {v[4], v[5], v[6], v[7]};
    *(s16x4*)&tile[trow][seg * 8] = lo;
    *(s16x4*)&tile[trow][seg * 8 + 4] = hi;
  }
  __syncthreads();
#pragma unroll
  for (int i2 = 0; i2 < 2; i2++) {
    int c = i2 * 256 + tid;
    int d = c >> 3, ts = c & 7;
    bf16x8 o;
#pragma unroll
    for (int j = 0; j < 8; j++) o[j] = tile[ts * 8 + j][d];
    *(bf16x8*)((short*)vT + (size_t)bh * TDH * TS + (size_t)d * TS +
               tb * 64 + ts * 8) = o;
  }
}

// ---------------- sliding-window attention (MFMA) --------------------------
__global__ __launch_bounds__(256) void k_attn(
    const __hip_bfloat16* __restrict__ qkv, const __hip_bfloat16* __restrict__ vT,
    const float* __restrict__ rpe, __hip_bfloat16* __restrict__ out) {
  __shared__ __align__(16) short K_lds[128 * 64];
  __shared__ __align__(16) short VT_lds[64 * 128];
  __shared__ __align__(16) short P_lds[4][16 * 136];
  __shared__ float rpe_lds[TC];
  int tid = threadIdx.x, lane = tid & 63, wave = tid >> 6;
  int fr = lane & 15, g = lane >> 4;
  int blk = blockIdx.x;
  int qt = blk & 31, bh = blk >> 5;
  int h = bh & 15, b = bh >> 4;
  int t0 = qt * 64;
  const short* qg = (const short*)qkv;

  if (tid < TC) rpe_lds[tid] = rpe[h * TC + tid];

#pragma unroll
  for (int i = 0; i < 4; i++) {
    int cb = i * 256 + wave * 64;
    int c = cb + lane;
    int row = c >> 3, slot = c & 7;
    int seg = slot ^ (row & 7);
    int kr = t0 - 64 + row; if (kr < 0) kr = 0;
    GLD16(qg + ((size_t)(b * TS + kr) * 3072 + 1024 + h * TDH + seg * 8),
          (char*)K_lds + cb * 16);
  }
  const short* vg = (const short*)vT + (size_t)bh * TDH * TS;
#pragma unroll
  for (int i = 0; i < 4; i++) {
    int cb = i * 256 + wave * 64;
    int c = cb + lane;
    int row = c >> 4, slot = c & 15;
    int seg = slot ^ (row & 15);
    int tc = t0 - 64 + seg * 8; if (tc < 0) tc = 0;
    GLD16(vg + (size_t)row * TS + tc, (char*)VT_lds + cb * 16);
  }

  int qrow = t0 + wave * 16 + fr;
  const short* qptr = qg + ((size_t)(b * TS + qrow) * 3072 + h * TDH + g * 8);
  bf16x8 qf0 = *(const bf16x8*)qptr;
  bf16x8 qf1 = *(const bf16x8*)(qptr + 32);

  __syncthreads();

  f32x4 S[8] = {};
#pragma unroll
  for (int kk = 0; kk < 2; kk++) {
    bf16x8 a = kk ? qf1 : qf0;
#pragma unroll
    for (int nt = 0; nt < 8; nt++) {
      int row = nt * 16 + fr;
      int slot = (kk * 4 + g) ^ (row & 7);
      bf16x8 bfrag = *(const bf16x8*)((const char*)K_lds + row * 128 + slot * 16);
      S[nt] = __builtin_amdgcn_mfma_f32_16x16x32_bf16(a, bfrag, S[nt], 0, 0, 0);
    }
  }

  int wq = wave * 16;
#pragma unroll
  for (int r = 0; r < 4; r++) {
    int ql = g * 4 + r;
    float sc[8];
    float m = -3.4028235e38f;
#pragma unroll
    for (int nt = 0; nt < 8; nt++) {
      int jj = nt * 16 + fr;
      int d = wq + ql + 64 - jj;
      bool valid = (d >= 0) && (d < TC) && (t0 - 64 + jj >= 0);
      float v = valid ? (S[nt][r] * 0.125f + rpe_lds[d & (TC - 1)])
                      : -3.4028235e38f;
      sc[nt] = v;
      m = fmaxf(m, v);
    }
#pragma unroll
    for (int o = 1; o < 16; o <<= 1) m = fmaxf(m, __shfl_xor(m, o));
    float p[8], sum = 0.f;
#pragma unroll
    for (int nt = 0; nt < 8; nt++) { p[nt] = __expf(sc[nt] - m); sum += p[nt]; }
#pragma unroll
    for (int o = 1; o < 16; o <<= 1) sum += __shfl_xor(sum, o);
    float rs = 1.0f / sum;
#pragma unroll
    for (int nt = 0; nt < 8; nt++)
      P_lds[wave][ql * 136 + nt * 16 + fr] = f2bf(p[nt] * rs);
  }

  f32x4 O[4] = {};
#pragma unroll
  for (int kk = 0; kk < 4; kk++) {
    bf16x8 pa = *(const bf16x8*)((const char*)&P_lds[wave][0] +
                                 fr * 272 + kk * 64 + g * 16);
#pragma unroll
    for (int dt = 0; dt < 4; dt++) {
      int row = dt * 16 + fr;
      int slot = (kk * 4 + g) ^ (row & 15);
      bf16x8 vb = *(const bf16x8*)((const char*)VT_lds + row * 256 + slot * 16);
      O[dt] = __builtin_amdgcn_mfma_f32_16x16x32_bf16(pa, vb, O[dt], 0, 0, 0);
    }
  }

  size_t ob = ((size_t)(b * TS + t0 + wq + g * 4)) * TD + h * TDH;
#pragma unroll
  for (int dt = 0; dt < 4; dt++)
#pragma unroll
    for (int r = 0; r < 4; r++)
      ((short*)out)[ob + (size_t)r * TD + dt * 16 + fr] = f2bf(O[dt][r]);
}

// ---------------- LayerNorm (two-pass, fused residual + split-K sum) ------
DEVI float block_sum(float v, float* red) {
  for (int o = 32; o; o >>= 1) v += __shfl_xor(v, o);
  int wave = threadIdx.x >> 6;
  if ((threadIdx.x & 63) == 0) red[wave] = v;
  __syncthreads();
  float r = red[0] + red[1] + red[2] + red[3];
  __syncthreads();
  return r;
}

// ln1: in = h (bf16) + P0 + P1 (bf16 split-K partials); out bf16 only.
// hB aliases outb: each thread reads its own 4 elems before writing them.
__global__ __launch_bounds__(256) void k_ln1(
    const __hip_bfloat16* __restrict__ hB, const __hip_bfloat16* __restrict__ P0,
    const __hip_bfloat16* __restrict__ P1, const float* __restrict__ scale,
    const float* __restrict__ offset, __hip_bfloat16* __restrict__ outb) {
  __shared__ float red[4];
  int row = blockIdx.x, tid = threadIdx.x;
  size_t base = (size_t)row * TD + tid * 4;
  s16x4 hv = *(const s16x4*)((const short*)hB + base);
  s16x4 a0 = *(const s16x4*)((const short*)P0 + base);
  s16x4 a1 = *(const s16x4*)((const short*)P1 + base);
  f32x4 xv;
  for (int j = 0; j < 4; j++) xv[j] = bf2f(hv[j]) + bf2f(a0[j]) + bf2f(a1[j]);
  float s = xv[0] + xv[1] + xv[2] + xv[3];
  s = block_sum(s, red);
  float mu = s * (1.f / TD);
  float s2 = 0.f;
  for (int j = 0; j < 4; j++) { float dlt = xv[j] - mu; s2 += dlt * dlt; }
  s2 = block_sum(s2, red);
  float rs = rsqrtf(s2 * (1.f / TD) + 1e-5f);
  f32x4 sc = *(const f32x4*)(scale + tid * 4);
  f32x4 of = *(const f32x4*)(offset + tid * 4);
  s16x4 pb;
  for (int j = 0; j < 4; j++)
    pb[j] = f2bf((xv[j] - mu) * rs * sc[j] + of[j]);
  *(s16x4*)((short*)outb + base) = pb;
}

// ln2: in = P0+P1+P2+P3 (bf16 partials) + attn residual (bf16) + bias;
// out f32 (d_out)
__global__ __launch_bounds__(256) void k_ln2(
    const __hip_bfloat16* __restrict__ P0, const __hip_bfloat16* __restrict__ P1,
    const __hip_bfloat16* __restrict__ P2, const __hip_bfloat16* __restrict__ P3,
    const __hip_bfloat16* __restrict__ R, const float* __restrict__ bias,
    const float* __restrict__ scale, const float* __restrict__ offset,
    float* __restrict__ outf) {
  __shared__ float red[4];
  int row = blockIdx.x, tid = threadIdx.x;
  size_t base = (size_t)row * TD + tid * 4;
  s16x4 a0 = *(const s16x4*)((const short*)P0 + base);
  s16x4 a1 = *(const s16x4*)((const short*)P1 + base);
  s16x4 a2 = *(const s16x4*)((const short*)P2 + base);
  s16x4 a3 = *(const s16x4*)((const short*)P3 + base);
  s16x4 rv = *(const s16x4*)((const short*)R + base);
  f32x4 bi = *(const f32x4*)(bias + tid * 4);
  f32x4 xv;
  for (int j = 0; j < 4; j++)
    xv[j] = bf2f(a0[j]) + bf2f(a1[j]) + bf2f(a2[j]) + bf2f(a3[j]) +
            bf2f(rv[j]) + bi[j];
  float s = xv[0] + xv[1] + xv[2] + xv[3];
  s = block_sum(s, red);
  float mu = s * (1.f / TD);
  float s2 = 0.f;
  for (int j = 0; j < 4; j++) { float dlt = xv[j] - mu; s2 += dlt * dlt; }
  s2 = block_sum(s2, red);
  float rs = rsqrtf(s2 * (1.f / TD) + 1e-5f);
  f32x4 sc = *(const f32x4*)(scale + tid * 4);
  f32x4 of = *(const f32x4*)(offset + tid * 4);
  f32x4 y;
  for (int j = 0; j < 4; j++) y[j] = (xv[j] - mu) * rs * sc[j] + of[j];
  *(f32x4*)(outf + base) = y;
}

// --------------------------------------------------------------------------
extern "C" void kernel_launch(void* const* d_in, const int* in_sizes, int n_in,
                              void* d_out, int out_size, void* d_ws, size_t ws_size,
                              hipStream_t stream) {
  const float* x    = (const float*)d_in[0];
  const float* pos  = (const float*)d_in[2];
  const float* rpe  = (const float*)d_in[3];
  const float* Wq   = (const float*)d_in[4];
  const float* Wk   = (const float*)d_in[5];
  const float* Wv   = (const float*)d_in[6];
  const float* Wo   = (const float*)d_in[7];
  const float* ln1s = (const float*)d_in[8];
  const float* ln1o = (const float*)d_in[9];
  const float* W1   = (const float*)d_in[10];
  const float* b1   = (const float*)d_in[11];
  const float* W2   = (const float*)d_in[12];
  const float* b2   = (const float*)d_in[13];
  const float* ln2s = (const float*)d_in[14];
  const float* ln2o = (const float*)d_in[15];

  char* ws = (char*)d_ws;
  const size_t MB = 1ull << 20;
  __hip_bfloat16* WqkvT = (__hip_bfloat16*)(ws + 0 * MB);   // 6 MB
  __hip_bfloat16* WoT   = (__hip_bfloat16*)(ws + 6 * MB);   // 2 MB
  __hip_bfloat16* W1T   = (__hip_bfloat16*)(ws + 8 * MB);   // 8 MB
  __hip_bfloat16* W2T   = (__hip_bfloat16*)(ws + 16 * MB);  // 8 MB
  __hip_bfloat16* hB    = (__hip_bfloat16*)(ws + 24 * MB);  // 8 MB (h until ln1)
  __hip_bfloat16* qkv   = (__hip_bfloat16*)(ws + 32 * MB);  // 24 MB
  __hip_bfloat16* aoB   = (__hip_bfloat16*)(ws + 56 * MB);  // 8 MB
  __hip_bfloat16* oB2   = (__hip_bfloat16*)(ws + 64 * MB);  // 16 MB, 2 bf16 partials
  __hip_bfloat16* atB   = (__hip_bfloat16*)(ws + 24 * MB);  // 8 MB (aliases hB; RMW-safe)
  __hip_bfloat16* ff1   = (__hip_bfloat16*)(ws + 32 * MB);  // 32 MB (aliases qkv+aoB)
  __hip_bfloat16* ff2   = (__hip_bfloat16*)(ws + 64 * MB);  // 32 MB, 4 bf16 partials
  __hip_bfloat16* vTb   = (__hip_bfloat16*)(ws + 112 * MB); // 8 MB
  // high-water: 120 MB

  dim3 blk(256), blk5(512);

  k_trans_all<<<16384, blk, 0, stream>>>(Wq, Wk, Wv, Wo, W1, W2,
                                         WqkvT, WoT, W1T, W2T, x, pos, hB);

  // QKV fused: (4096 x 1024) * (3072 x 1024)^T -> bf16 qkv
  // BN=192 -> grid 16 x 16 = 256 blocks (full CU coverage; was 192)
  k_g64<192, 0><<<dim3(TM / 256, 3072 / 192, 1), blk5, 0, stream>>>(
      hB, WqkvT, qkv, nullptr, TM, 3072, TD, TD, TD);

  k_vtrans<<<dim3(TB * TH, TS / 64), blk, 0, stream>>>(qkv, vTb);
  k_attn<<<TB * TH * (TS / 64), blk, 0, stream>>>(qkv, vTb, rpe, aoB);

  // Wo: BN=128, split-K=2 -> two bf16 partials (r8-proven path)
  k_gemm8<128, 2><<<dim3(TM / 256, TD / 128, 2), blk5, 0, stream>>>(
      aoB, WoT, oB2, nullptr, TM, TD, TD / 2, TD, TD);

  k_ln1<<<TM, blk, 0, stream>>>(hB, oB2, oB2 + (size_t)TM * TD, ln1s, ln1o, atB);

  // FFN1: bias+relu -> bf16 (grid 16x16 = 256 blocks)
  k_g64<256, 1><<<dim3(TM / 256, TFF / 256, 1), blk5, 0, stream>>>(
      atB, W1T, ff1, b1, TM, TFF, TD, TD, TD);

  // FFN2: BN=256, split-K=4 -> four bf16 partials (grid 16x4x4 = 256 blocks)
  k_g64<256, 2><<<dim3(TM / 256, TD / 256, 4), blk5, 0, stream>>>(
      ff1, W2T, ff2, nullptr, TM, TD, TFF / 4, TFF, TFF);

  k_ln2<<<TM, blk, 0, stream>>>(ff2, ff2 + (size_t)TM * TD,
                                ff2 + (size_t)2 * TM * TD, ff2 + (size_t)3 * TM * TD,
                                atB, b2, ln2s, ln2o, (float*)d_out);
}